// Round 8
// baseline (295.047 us; speedup 1.0000x reference)
//
#include <hip/hip_runtime.h>

// SelfAttention3d: B=4, C=128, D=16, H=W=64.
//   K0 prep  : 6 weight mats f32 -> bf16, pre-swizzled halved tables in ws
//   K1 qkv   : 512-s strip/WG, 2 WG/CU (W cycled through 32KB buffer via
//              glds + counted vmcnt), XCD-chunked block swizzle
//   K2 attn  : per (b,c,d) 64x64; PV swapped -> direct b64 O stores
//   K3 tail  : a1+relu -> a2 (LDS chain) -> f swapped -> f32x4 stores

#define CCH 128
#define SPB 65536      // per-batch spatial = D*H*W
#define NBATCH 4
#define WTAB 16384     // elements per 128x128 weight table

typedef float f32x4 __attribute__((ext_vector_type(4)));
typedef __bf16 bf16x8 __attribute__((ext_vector_type(8)));
typedef short s16x8 __attribute__((ext_vector_type(8)));
typedef unsigned short u16x8 __attribute__((ext_vector_type(8)));
typedef unsigned short u16x4 __attribute__((ext_vector_type(4)));
typedef unsigned int u32x2 __attribute__((ext_vector_type(2)));

// ---- MFMA wrapper: robust to builtin signature (v8i16 vs v8bf16) ----
template <typename T>
static __device__ __forceinline__ auto mfma_try(T a, T b, f32x4 c, int)
    -> decltype(__builtin_amdgcn_mfma_f32_16x16x32_bf16(a, b, c, 0, 0, 0)) {
  return __builtin_amdgcn_mfma_f32_16x16x32_bf16(a, b, c, 0, 0, 0);
}
template <typename T>
static __device__ __forceinline__ f32x4 mfma_try(T a, T b, f32x4 c, long) {
  return __builtin_amdgcn_mfma_f32_16x16x32_bf16(
      __builtin_bit_cast(bf16x8, a), __builtin_bit_cast(bf16x8, b), c, 0, 0, 0);
}
static __device__ __forceinline__ f32x4 MFMA16(u16x8 a, u16x8 b, f32x4 c) {
  return mfma_try(__builtin_bit_cast(s16x8, a), __builtin_bit_cast(s16x8, b), c, 0);
}

static __device__ __forceinline__ unsigned short f2b(float f) {
  return __builtin_bit_cast(unsigned short, (__bf16)f);
}
static __device__ __forceinline__ unsigned int pk2(float a, float b) {
  return (unsigned int)f2b(a) | ((unsigned int)f2b(b) << 16);
}

// async global->LDS, 16B per lane (linear dest, pre-swizzled source tables)
static __device__ __forceinline__ void glds16(const unsigned short* g,
                                              unsigned short* l) {
  __builtin_amdgcn_global_load_lds(
      (const __attribute__((address_space(1))) unsigned int*)g,
      (__attribute__((address_space(3))) unsigned int*)l, 16, 0, 0);
}

// barriers (T4 pattern)
static __device__ __forceinline__ void bar_lgkm() {
  asm volatile("s_waitcnt lgkmcnt(0)" ::: "memory");
  __builtin_amdgcn_sched_barrier(0);
  __builtin_amdgcn_s_barrier();
  __builtin_amdgcn_sched_barrier(0);
}
static __device__ __forceinline__ void bar_vm0() {
  asm volatile("s_waitcnt vmcnt(0)" ::: "memory");
  __builtin_amdgcn_sched_barrier(0);
  __builtin_amdgcn_s_barrier();
  __builtin_amdgcn_sched_barrier(0);
}
// keep 4 newest VMEM (this conv's stores) in flight; drain older (glds/loads)
static __device__ __forceinline__ void bar_vm4_lgkm() {
  asm volatile("s_waitcnt vmcnt(4) lgkmcnt(0)" ::: "memory");
  __builtin_amdgcn_sched_barrier(0);
  __builtin_amdgcn_s_barrier();
  __builtin_amdgcn_sched_barrier(0);
}

// --- swizzles (element index), bijective per row ---
static __device__ __forceinline__ int swzc(int r, int c) {   // 128-col u16 tile
  int slot = ((c >> 3) ^ (r & 7) ^ ((r >> 3) & 15)) & 15;
  return r * 128 + slot * 8 + (c & 7);
}
static __device__ __forceinline__ int widx(int r, int c) {   // halved W table
  return (r & 64) * 128 + swzc(r & 63, c);
}
// C repack tile [o][s] u16 (qkv): b64 epilogue writes + 256B readback rows.
static __device__ __forceinline__ int cbix(int o, int s) {
  int slot = ((s >> 3) ^ (o & 15)) & 15;
  return o * 128 + slot * 8 + (s & 7);
}
static __device__ __forceinline__ int swat(int w, int x) {   // 64-col attn tile
  int slot = ((x >> 3) ^ (w & 7) ^ ((w >> 3) & 7)) & 7;
  return w * 64 + slot * 8 + (x & 7);
}
static __device__ __forceinline__ int pix(int i, int j) {    // attn P tile
  int slot = ((j >> 3) ^ (((i >> 2) & 3) << 1)) & 7;
  return i * 64 + slot * 8 + (j & 7);
}

// ---------------------------------------------------------------------------
// K0: weights f32 -> bf16 into halved swizzled tables (rows 0-63 | 64-127).
// ---------------------------------------------------------------------------
__global__ __launch_bounds__(256) void prep_w_kernel(
    const float* __restrict__ Wq, const float* __restrict__ Wk,
    const float* __restrict__ Wv, const float* __restrict__ W1,
    const float* __restrict__ W2, const float* __restrict__ W3,
    unsigned short* __restrict__ out)
{
  const float* Ws[6] = {Wq, Wk, Wv, W1, W2, W3};
  const float* W = Ws[blockIdx.x];
  unsigned short* o = out + (size_t)blockIdx.x * WTAB;
  const int tid = threadIdx.x;
#pragma unroll
  for (int p = 0; p < 16; ++p) {
    const int base = p * 1024 + tid * 4;
    const int m = base >> 7;
    const int c0 = base & 127;
    f32x4 v = *(const f32x4*)&W[base];
    u16x4 u;
#pragma unroll
    for (int e = 0; e < 4; ++e) u[e] = f2b(v[e]);
    *(u16x4*)&o[widx(m, c0)] = u;
  }
}

// ---------------------------------------------------------------------------
// K1: fused QKV. 512 WGs x 512 thr, strip = 512 s, 2 WG/CU.
// W cycled q->k->v->(q') through one 32KB buffer via glds; counted vmcnt
// keeps C-stores in flight while draining W loads.
// ---------------------------------------------------------------------------
__global__ __launch_bounds__(512, 4) void qkv_kernel(
    const float* __restrict__ X, const unsigned short* __restrict__ Wbf,
    const float* __restrict__ Bq, const float* __restrict__ Bk,
    const float* __restrict__ Bv,
    unsigned short* __restrict__ Yq, unsigned short* __restrict__ Yk,
    unsigned short* __restrict__ Yv)
{
  __shared__ unsigned short wt[WTAB];      // 32KB current W image
  __shared__ unsigned short xb[WTAB];      // 32KB X^T stage / C repack
  __shared__ float bias_lds[3][128];

  const int tid  = threadIdx.x;
  const int wv   = tid >> 6;
  const int lane = tid & 63;
  const int lr   = lane & 15;
  const int lg   = lane >> 4;
  // XCD-chunked swizzle: each XCD owns 64 contiguous strips (32K s range)
  const int lin  = blockIdx.x;
  const int swz  = ((lin & 7) << 6) | (lin >> 3);
  const int sbase = (swz & 127) * 512;
  const size_t xoff = (size_t)(swz >> 7) * CCH * SPB;
  const int go = tid * 8;

  // ---- prologue: issue Wq glds, stage bias + X sub-tile 0 ----
#pragma unroll
  for (int p = 0; p < 4; ++p) glds16(&Wbf[p * 4096 + go], &wt[p * 4096 + go]);

  if (tid < 128) {
    bias_lds[0][tid] = Bq[tid];
    bias_lds[1][tid] = Bk[tid];
    bias_lds[2][tid] = Bv[tid];
  }

  const int c0  = (tid >> 3) * 2;          // c-pair owned by this thread
  const int sb8 = (tid & 7) * 4;           // s start within 32-s quarter
  const float* xrow = X + xoff + (size_t)c0 * SPB + sbase;
  unsigned int* xb32 = (unsigned int*)xb;

  f32x4 xr[8];
#pragma unroll
  for (int i = 0; i < 4; ++i) {
    xr[i]     = *(const f32x4*)&xrow[sb8 + 32 * i];
    xr[4 + i] = *(const f32x4*)&xrow[SPB + sb8 + 32 * i];
  }
#pragma unroll
  for (int i = 0; i < 4; ++i)
#pragma unroll
    for (int e = 0; e < 4; ++e)
      xb32[swzc(sb8 + 32 * i + e, c0) >> 1] = pk2(xr[i][e], xr[4 + i][e]);
  __syncthreads();   // S0: X0 staged, Wq resident (full drain)

#pragma unroll
  for (int si = 0; si < 4; ++si) {
    const int sg = sbase + si * 128;

    // ---- A-frags for this sub-tile -> regs ----
    u16x8 afr[4];
#pragma unroll
    for (int ks = 0; ks < 4; ++ks)
      afr[ks] = *(const u16x8*)&xb[swzc(wv * 16 + lr, ks * 32 + lg * 8)];

    // ---- T14: issue next X sub-tile loads (consumed at loop tail) ----
    if (si < 3) {
      const float* xn = xrow + (si + 1) * 128;
#pragma unroll
      for (int i = 0; i < 4; ++i) {
        xr[i]     = *(const f32x4*)&xn[sb8 + 32 * i];
        xr[4 + i] = *(const f32x4*)&xn[SPB + sb8 + 32 * i];
      }
    }
    bar_lgkm();   // afr reads done by all waves; xb free for repack

    // ---- one conv: GEMM from wt, prefetch next W, repack, 256B stores ----
    auto conv = [&](int ci, const unsigned short* Wnext,
                    unsigned short* __restrict__ Y, bool last) {
      f32x4 acc[8];
#pragma unroll
      for (int of = 0; of < 8; ++of) {
        f32x4 z = {0.f, 0.f, 0.f, 0.f};
        acc[of] = z;
      }
#pragma unroll
      for (int ks = 0; ks < 4; ++ks) {
        const int k0 = ks * 32 + lg * 8;
#pragma unroll
        for (int of = 0; of < 8; ++of) {
          u16x8 wfr = *(const u16x8*)&wt[widx(of * 16 + lr, k0)];
          acc[of] = MFMA16(afr[ks], wfr, acc[of]);   // D[s][o] per lane
        }
      }
      bar_lgkm();   // all waves' wt reads done -> wt reusable
      if (Wnext) {
#pragma unroll
        for (int p = 0; p < 4; ++p)
          glds16(&Wnext[p * 4096 + go], &wt[p * 4096 + go]);
      }
      // epilogue: bias + cvt_pk -> b64 repack writes (s-major rows of xb)
#pragma unroll
      for (int of = 0; of < 8; ++of) {
        const float b = bias_lds[ci][of * 16 + lr];
        u32x2 pk;
        pk.x = pk2(acc[of][0] + b, acc[of][1] + b);
        pk.y = pk2(acc[of][2] + b, acc[of][3] + b);
        *(u32x2*)&xb[cbix(of * 16 + lr, wv * 16 + lg * 4)] = pk;
      }
      bar_lgkm();   // repack visible
      // readback: 4 rows x 256B contiguous per wave instruction
#pragma unroll
      for (int p = 0; p < 4; ++p) {
        const int row = p * 32 + (tid >> 4);
        const int sc  = (tid & 15) * 8;
        u16x8 v = *(const u16x8*)&xb[cbix(row, sc)];
        *(u16x8*)&Y[xoff + (size_t)row * SPB + sg + sc] = v;
      }
      // drain glds (next W resident) + readback ds reads; keep 4 stores live
      if (!last) bar_vm4_lgkm();
    };

    conv(0, Wbf + WTAB,     Yq, false);
    conv(1, Wbf + 2 * WTAB, Yk, false);
    conv(2, si < 3 ? Wbf : nullptr, Yv, si == 3);

    // ---- stage next sub-tile from prefetched regs ----
    if (si < 3) {
#pragma unroll
      for (int i = 0; i < 4; ++i)
#pragma unroll
        for (int e = 0; e < 4; ++e)
          xb32[swzc(sb8 + 32 * i + e, c0) >> 1] = pk2(xr[i][e], xr[4 + i][e]);
      bar_lgkm();   // staged; Wq already resident from conv2's bar
    }
  }
}

// ---------------------------------------------------------------------------
// K2: attention per (b,c,d) 64x64 slice (R7 body + XCD swizzle).
// ---------------------------------------------------------------------------
__global__ __launch_bounds__(256, 4) void attn64_kernel(
    const unsigned short* __restrict__ Q,
    const unsigned short* __restrict__ K,
    const unsigned short* __restrict__ V,
    unsigned short* __restrict__ O)
{
  __shared__ unsigned short qt[4096];   // Q^T[w][x]
  __shared__ unsigned short kt[4096];   // K^T[w][x]
  __shared__ unsigned short vt[4096];   // V^T[w][x]
  __shared__ unsigned short pbuf[4096]; // P rows (wave-private)

  const int tid  = threadIdx.x;
  const int wv   = tid >> 6;
  const int lane = tid & 63;
  const int lr   = lane & 15;
  const int lg   = lane >> 4;
  const int bid  = blockIdx.x;                       // 8192 = 8 * 1024
  const int bs   = ((bid & 7) << 10) | (bid >> 3);   // XCD-chunked
  const size_t base = (size_t)bs * 4096;

  {
    const int x0 = (tid >> 3) * 2;
    const int w0 = (tid & 7) * 8;
    const size_t ga = base + (size_t)x0 * 64 + w0;
    u16x8 qa = *(const u16x8*)&Q[ga], qb = *(const u16x8*)&Q[ga + 64];
    u16x8 ka = *(const u16x8*)&K[ga], kb = *(const u16x8*)&K[ga + 64];
    u16x8 va = *(const u16x8*)&V[ga], vb = *(const u16x8*)&V[ga + 64];
    unsigned int* qt32 = (unsigned int*)qt;
    unsigned int* kt32 = (unsigned int*)kt;
    unsigned int* vt32 = (unsigned int*)vt;
#pragma unroll
    for (int e = 0; e < 8; ++e) {
      const int idx = swat(w0 + e, x0) >> 1;
      qt32[idx] = (unsigned int)qa[e] | ((unsigned int)qb[e] << 16);
      kt32[idx] = (unsigned int)ka[e] | ((unsigned int)kb[e] << 16);
      vt32[idx] = (unsigned int)va[e] | ((unsigned int)vb[e] << 16);
    }
  }
  __syncthreads();

  f32x4 sacc[4];
#pragma unroll
  for (int nf = 0; nf < 4; ++nf) { f32x4 z = {0.f, 0.f, 0.f, 0.f}; sacc[nf] = z; }
#pragma unroll
  for (int ks = 0; ks < 2; ++ks) {
    const int k0 = ks * 32 + lg * 8;
    u16x8 a = *(const u16x8*)&qt[swat(wv * 16 + lr, k0)];
#pragma unroll
    for (int nf = 0; nf < 4; ++nf) {
      u16x8 bb = *(const u16x8*)&kt[swat(nf * 16 + lr, k0)];
      sacc[nf] = MFMA16(a, bb, sacc[nf]);
    }
  }

#pragma unroll
  for (int r = 0; r < 4; ++r) {
    float m = fmaxf(fmaxf(sacc[0][r], sacc[1][r]), fmaxf(sacc[2][r], sacc[3][r]));
    m = fmaxf(m, __shfl_xor(m, 1));
    m = fmaxf(m, __shfl_xor(m, 2));
    m = fmaxf(m, __shfl_xor(m, 4));
    m = fmaxf(m, __shfl_xor(m, 8));
    float sum = 0.f;
#pragma unroll
    for (int nf = 0; nf < 4; ++nf) {
      float p = __expf(sacc[nf][r] - m);
      sacc[nf][r] = p;
      sum += p;
    }
    sum += __shfl_xor(sum, 1);
    sum += __shfl_xor(sum, 2);
    sum += __shfl_xor(sum, 4);
    sum += __shfl_xor(sum, 8);
    const float inv = 1.f / sum;
    const int i = wv * 16 + lg * 4 + r;
#pragma unroll
    for (int nf = 0; nf < 4; ++nf)
      pbuf[pix(i, nf * 16 + lr)] = f2b(sacc[nf][r] * inv);
  }

  f32x4 oacc[4];
#pragma unroll
  for (int nf = 0; nf < 4; ++nf) { f32x4 z = {0.f, 0.f, 0.f, 0.f}; oacc[nf] = z; }
#pragma unroll
  for (int ks = 0; ks < 2; ++ks) {
    const int k0 = ks * 32 + lg * 8;
    u16x8 a = *(const u16x8*)&pbuf[pix(wv * 16 + lr, k0)];
#pragma unroll
    for (int nf = 0; nf < 4; ++nf) {
      u16x8 bb = *(const u16x8*)&vt[swat(nf * 16 + lr, k0)];
      oacc[nf] = MFMA16(bb, a, oacc[nf]);   // swapped args
    }
  }

  {
    const size_t ib = base + (size_t)(16 * wv + lr) * 64 + lg * 4;
#pragma unroll
    for (int nf = 0; nf < 4; ++nf) {
      u32x2 pk;
      pk.x = pk2(oacc[nf][0], oacc[nf][1]);
      pk.y = pk2(oacc[nf][2], oacc[nf][3]);
      *(u32x2*)&O[ib + nf * 16] = pk;
    }
  }
}

// ---------------------------------------------------------------------------
// K3: tail a1+relu -> a2 -> f (R7 body + XCD swizzle on bx).
// ---------------------------------------------------------------------------
__global__ __launch_bounds__(256, 2) void tail_kernel(
    const unsigned short* __restrict__ Xb, const unsigned short* __restrict__ Wbf,
    const float* __restrict__ B1, const float* __restrict__ B2,
    const float* __restrict__ B3, float* __restrict__ OUT)
{
  __shared__ unsigned short wl[16384];   // W full (halved-table image)
  __shared__ unsigned short xc[16384];   // chain tile [s][c]
  __shared__ float bias_lds[3][128];

  const int tid  = threadIdx.x;
  const int wv   = tid >> 6;
  const int lane = tid & 63;
  const int lr   = lane & 15;
  const int lg   = lane >> 4;
  const int bx   = blockIdx.x;                      // 512 = 8 * 64
  const int bxs  = ((bx & 7) << 6) | (bx >> 3);     // XCD-chunked
  const int s0   = bxs * 128;
  const size_t xbase = (size_t)blockIdx.y * CCH * SPB;
  const int go = tid * 8;

#pragma unroll
  for (int p = 0; p < 8; ++p) glds16(&Wbf[p * 2048 + go], &wl[p * 2048 + go]);

  if (tid < 128) {
    bias_lds[0][tid] = B1[tid];
    bias_lds[1][tid] = B2[tid];
    bias_lds[2][tid] = B3[tid];
  }

  {
    const int cp = tid >> 2;
    const int sq = tid & 3;
    const unsigned short* xa = Xb + xbase + (size_t)(2 * cp) * SPB + s0 + sq * 32;
    const unsigned short* xb = xa + SPB;
    unsigned int* xc32 = (unsigned int*)xc;
#pragma unroll
    for (int i = 0; i < 4; ++i) {
      u16x8 a = *(const u16x8*)&xa[8 * i];
      u16x8 b = *(const u16x8*)&xb[8 * i];
#pragma unroll
      for (int e = 0; e < 8; ++e)
        xc32[swzc(sq * 32 + 8 * i + e, 2 * cp) >> 1] =
            (unsigned int)a[e] | ((unsigned int)b[e] << 16);
    }
  }
  __syncthreads();   // S1: stage + W1 resident

  u16x8 bfr[2][4];
#pragma unroll
  for (int nf = 0; nf < 2; ++nf)
#pragma unroll
    for (int ks = 0; ks < 4; ++ks)
      bfr[nf][ks] = *(const u16x8*)&xc[swzc(wv * 32 + nf * 16 + lr, ks * 32 + lg * 8)];

  f32x4 acc[8][2];
  auto gemm_std = [&]() {
#pragma unroll
    for (int mf = 0; mf < 8; ++mf)
#pragma unroll
      for (int nf = 0; nf < 2; ++nf) {
        f32x4 z = {0.f, 0.f, 0.f, 0.f};
        acc[mf][nf] = z;
      }
#pragma unroll
    for (int ks = 0; ks < 4; ++ks) {
      const int k0 = ks * 32 + lg * 8;
#pragma unroll
      for (int mf = 0; mf < 8; ++mf) {
        u16x8 afr = *(const u16x8*)&wl[widx(mf * 16 + lr, k0)];
        acc[mf][0] = MFMA16(afr, bfr[0][ks], acc[mf][0]);
        acc[mf][1] = MFMA16(afr, bfr[1][ks], acc[mf][1]);
      }
    }
  };

  auto epi_chain = [&](int ci, bool relu) {
#pragma unroll
    for (int mf = 0; mf < 8; ++mf)
#pragma unroll
      for (int nf = 0; nf < 2; ++nf) {
        const int s = wv * 32 + nf * 16 + lr;
        const int cc = mf * 16 + lg * 4;
        f32x4 bb = *(const f32x4*)&bias_lds[ci][cc];
        float v0 = acc[mf][nf][0] + bb[0];
        float v1 = acc[mf][nf][1] + bb[1];
        float v2 = acc[mf][nf][2] + bb[2];
        float v3 = acc[mf][nf][3] + bb[3];
        if (relu) {
          v0 = fmaxf(v0, 0.f); v1 = fmaxf(v1, 0.f);
          v2 = fmaxf(v2, 0.f); v3 = fmaxf(v3, 0.f);
        }
        u32x2 pk;
        pk.x = pk2(v0, v1);
        pk.y = pk2(v2, v3);
        *(u32x2*)&xc[swzc(s, cc)] = pk;
      }
#pragma unroll
    for (int nf = 0; nf < 2; ++nf)
#pragma unroll
      for (int ks = 0; ks < 4; ++ks)
        bfr[nf][ks] = *(const u16x8*)&xc[swzc(wv * 32 + nf * 16 + lr, ks * 32 + lg * 8)];
  };

#pragma unroll
  for (int j = 0; j < 2; ++j) {
    gemm_std();
    bar_lgkm();
    const unsigned short* Wn = Wbf + (size_t)(j + 1) * WTAB;
#pragma unroll
    for (int p = 0; p < 8; ++p) glds16(&Wn[p * 2048 + go], &wl[p * 2048 + go]);
    epi_chain(j, j == 0);
    bar_vm0();
  }

  {
    f32x4 acc3[2][8];
#pragma unroll
    for (int sf = 0; sf < 2; ++sf)
#pragma unroll
      for (int of = 0; of < 8; ++of) {
        f32x4 z = {0.f, 0.f, 0.f, 0.f};
        acc3[sf][of] = z;
      }
#pragma unroll
    for (int ks = 0; ks < 4; ++ks) {
      const int k0 = ks * 32 + lg * 8;
#pragma unroll
      for (int of = 0; of < 8; ++of) {
        u16x8 wfr = *(const u16x8*)&wl[widx(of * 16 + lr, k0)];
        acc3[0][of] = MFMA16(bfr[0][ks], wfr, acc3[0][of]);
        acc3[1][of] = MFMA16(bfr[1][ks], wfr, acc3[1][of]);
      }
    }
    const int sb = s0 + wv * 32 + lg * 4;
#pragma unroll
    for (int sf = 0; sf < 2; ++sf)
#pragma unroll
      for (int of = 0; of < 8; ++of) {
        const float b = bias_lds[2][of * 16 + lr];
        f32x4 v = acc3[sf][of];
        v[0] += b; v[1] += b; v[2] += b; v[3] += b;
        *(f32x4*)&OUT[xbase + (size_t)(of * 16 + lr) * SPB + sb + sf * 16] = v;
      }
  }
}

extern "C" void kernel_launch(void* const* d_in, const int* in_sizes, int n_in,
                              void* d_out, int out_size, void* d_ws, size_t ws_size,
                              hipStream_t stream) {
  const float* x   = (const float*)d_in[0];
  const float* Wq  = (const float*)d_in[1];  const float* bq  = (const float*)d_in[2];
  const float* Wk  = (const float*)d_in[3];  const float* bk  = (const float*)d_in[4];
  const float* Wv  = (const float*)d_in[5];  const float* bv  = (const float*)d_in[6];
  const float* Wa1 = (const float*)d_in[7];  const float* ba1 = (const float*)d_in[8];
  const float* Wa2 = (const float*)d_in[9];  const float* ba2 = (const float*)d_in[10];
  const float* Wf  = (const float*)d_in[11]; const float* bf_ = (const float*)d_in[12];

  // ws layout: q (67.1MB) then 6 bf16 weight tables (192KB).
  unsigned short* qb  = (unsigned short*)d_ws;
  unsigned short* wbf = qb + (size_t)NBATCH * CCH * SPB;
  // k,v packed into d_out (dead before final f32 write).
  unsigned short* kb = (unsigned short*)d_out;
  unsigned short* vb = kb + (size_t)NBATCH * CCH * SPB;

  prep_w_kernel<<<6, 256, 0, stream>>>(Wq, Wk, Wv, Wa1, Wa2, Wf, wbf);

  qkv_kernel<<<512, 512, 0, stream>>>(x, wbf, bq, bk, bv, qb, kb, vb);

  attn64_kernel<<<NBATCH * CCH * 16, 256, 0, stream>>>(qb, kb, vb, qb);

  tail_kernel<<<dim3(SPB / 128, NBATCH), 256, 0, stream>>>(
      qb, wbf + (size_t)3 * WTAB, ba1, ba2, bf_, (float*)d_out);
}

// Round 9
// 191.749 us; speedup vs baseline: 1.5387x; 1.5387x over previous
//
#include <hip/hip_runtime.h>

// SelfAttention3d: B=4, C=128, D=16, H=W=64.
//   K0 prep  : 6 weight mats f32 -> bf16, pre-swizzled halved tables in ws
//   K1 qkv   : 512-s strip/WG, 66KB LDS -> 2 WG/CU (W cycled through 32KB
//              buffer via glds + counted vmcnt), XCD-chunked block swizzle.
//              launch_bounds(512,2): do NOT cap VGPR (R8's (512,4) -> 64 VGPR
//              -> ~300MB scratch spill traffic, 2x regression).
//   K2 attn  : per (b,c,d) 64x64; PV swapped -> direct b64 O stores
//   K3 tail  : a1+relu -> a2 (LDS chain) -> f swapped -> f32x4 stores

#define CCH 128
#define SPB 65536      // per-batch spatial = D*H*W
#define NBATCH 4
#define WTAB 16384     // elements per 128x128 weight table

typedef float f32x4 __attribute__((ext_vector_type(4)));
typedef __bf16 bf16x8 __attribute__((ext_vector_type(8)));
typedef short s16x8 __attribute__((ext_vector_type(8)));
typedef unsigned short u16x8 __attribute__((ext_vector_type(8)));
typedef unsigned short u16x4 __attribute__((ext_vector_type(4)));
typedef unsigned int u32x2 __attribute__((ext_vector_type(2)));

// ---- MFMA wrapper: robust to builtin signature (v8i16 vs v8bf16) ----
template <typename T>
static __device__ __forceinline__ auto mfma_try(T a, T b, f32x4 c, int)
    -> decltype(__builtin_amdgcn_mfma_f32_16x16x32_bf16(a, b, c, 0, 0, 0)) {
  return __builtin_amdgcn_mfma_f32_16x16x32_bf16(a, b, c, 0, 0, 0);
}
template <typename T>
static __device__ __forceinline__ f32x4 mfma_try(T a, T b, f32x4 c, long) {
  return __builtin_amdgcn_mfma_f32_16x16x32_bf16(
      __builtin_bit_cast(bf16x8, a), __builtin_bit_cast(bf16x8, b), c, 0, 0, 0);
}
static __device__ __forceinline__ f32x4 MFMA16(u16x8 a, u16x8 b, f32x4 c) {
  return mfma_try(__builtin_bit_cast(s16x8, a), __builtin_bit_cast(s16x8, b), c, 0);
}

static __device__ __forceinline__ unsigned short f2b(float f) {
  return __builtin_bit_cast(unsigned short, (__bf16)f);
}
static __device__ __forceinline__ unsigned int pk2(float a, float b) {
  return (unsigned int)f2b(a) | ((unsigned int)f2b(b) << 16);
}

// async global->LDS, 16B per lane (linear dest, pre-swizzled source tables)
static __device__ __forceinline__ void glds16(const unsigned short* g,
                                              unsigned short* l) {
  __builtin_amdgcn_global_load_lds(
      (const __attribute__((address_space(1))) unsigned int*)g,
      (__attribute__((address_space(3))) unsigned int*)l, 16, 0, 0);
}

// barriers (T4 pattern)
static __device__ __forceinline__ void bar_lgkm() {
  asm volatile("s_waitcnt lgkmcnt(0)" ::: "memory");
  __builtin_amdgcn_sched_barrier(0);
  __builtin_amdgcn_s_barrier();
  __builtin_amdgcn_sched_barrier(0);
}
static __device__ __forceinline__ void bar_vm0() {
  asm volatile("s_waitcnt vmcnt(0)" ::: "memory");
  __builtin_amdgcn_sched_barrier(0);
  __builtin_amdgcn_s_barrier();
  __builtin_amdgcn_sched_barrier(0);
}
// keep 4 newest VMEM (this conv's stores) in flight; drain older (glds/loads)
static __device__ __forceinline__ void bar_vm4_lgkm() {
  asm volatile("s_waitcnt vmcnt(4) lgkmcnt(0)" ::: "memory");
  __builtin_amdgcn_sched_barrier(0);
  __builtin_amdgcn_s_barrier();
  __builtin_amdgcn_sched_barrier(0);
}

// --- swizzles (element index), bijective per row ---
static __device__ __forceinline__ int swzc(int r, int c) {   // 128-col u16 tile
  int slot = ((c >> 3) ^ (r & 7) ^ ((r >> 3) & 15)) & 15;
  return r * 128 + slot * 8 + (c & 7);
}
static __device__ __forceinline__ int widx(int r, int c) {   // halved W table
  return (r & 64) * 128 + swzc(r & 63, c);
}
// C repack tile [o][s] u16 (qkv): b64 epilogue writes + 256B readback rows.
static __device__ __forceinline__ int cbix(int o, int s) {
  int slot = ((s >> 3) ^ (o & 15)) & 15;
  return o * 128 + slot * 8 + (s & 7);
}
static __device__ __forceinline__ int swat(int w, int x) {   // 64-col attn tile
  int slot = ((x >> 3) ^ (w & 7) ^ ((w >> 3) & 7)) & 7;
  return w * 64 + slot * 8 + (x & 7);
}
static __device__ __forceinline__ int pix(int i, int j) {    // attn P tile
  int slot = ((j >> 3) ^ (((i >> 2) & 3) << 1)) & 7;
  return i * 64 + slot * 8 + (j & 7);
}

// ---------------------------------------------------------------------------
// K0: weights f32 -> bf16 into halved swizzled tables (rows 0-63 | 64-127).
// ---------------------------------------------------------------------------
__global__ __launch_bounds__(256) void prep_w_kernel(
    const float* __restrict__ Wq, const float* __restrict__ Wk,
    const float* __restrict__ Wv, const float* __restrict__ W1,
    const float* __restrict__ W2, const float* __restrict__ W3,
    unsigned short* __restrict__ out)
{
  const float* Ws[6] = {Wq, Wk, Wv, W1, W2, W3};
  const float* W = Ws[blockIdx.x];
  unsigned short* o = out + (size_t)blockIdx.x * WTAB;
  const int tid = threadIdx.x;
#pragma unroll
  for (int p = 0; p < 16; ++p) {
    const int base = p * 1024 + tid * 4;
    const int m = base >> 7;
    const int c0 = base & 127;
    f32x4 v = *(const f32x4*)&W[base];
    u16x4 u;
#pragma unroll
    for (int e = 0; e < 4; ++e) u[e] = f2b(v[e]);
    *(u16x4*)&o[widx(m, c0)] = u;
  }
}

// ---------------------------------------------------------------------------
// K1: fused QKV. 512 WGs x 512 thr, strip = 512 s. 66KB LDS -> 2 WG/CU.
// W cycled q->k->v->(q') through one 32KB buffer via glds; counted vmcnt
// keeps C-stores in flight while draining W loads.
// ---------------------------------------------------------------------------
__global__ __launch_bounds__(512, 2) void qkv_kernel(
    const float* __restrict__ X, const unsigned short* __restrict__ Wbf,
    const float* __restrict__ Bq, const float* __restrict__ Bk,
    const float* __restrict__ Bv,
    unsigned short* __restrict__ Yq, unsigned short* __restrict__ Yk,
    unsigned short* __restrict__ Yv)
{
  __shared__ unsigned short wt[WTAB];      // 32KB current W image
  __shared__ unsigned short xb[WTAB];      // 32KB X^T stage / C repack
  __shared__ float bias_lds[3][128];

  const int tid  = threadIdx.x;
  const int wv   = tid >> 6;
  const int lane = tid & 63;
  const int lr   = lane & 15;
  const int lg   = lane >> 4;
  // XCD-chunked swizzle: each XCD owns 64 contiguous strips (32K s range)
  const int lin  = blockIdx.x;
  const int swz  = ((lin & 7) << 6) | (lin >> 3);
  const int sbase = (swz & 127) * 512;
  const size_t xoff = (size_t)(swz >> 7) * CCH * SPB;
  const int go = tid * 8;

  // ---- prologue: issue Wq glds, stage bias + X sub-tile 0 ----
#pragma unroll
  for (int p = 0; p < 4; ++p) glds16(&Wbf[p * 4096 + go], &wt[p * 4096 + go]);

  if (tid < 128) {
    bias_lds[0][tid] = Bq[tid];
    bias_lds[1][tid] = Bk[tid];
    bias_lds[2][tid] = Bv[tid];
  }

  const int c0  = (tid >> 3) * 2;          // c-pair owned by this thread
  const int sb8 = (tid & 7) * 4;           // s start within 32-s quarter
  const float* xrow = X + xoff + (size_t)c0 * SPB + sbase;
  unsigned int* xb32 = (unsigned int*)xb;

  f32x4 xr[8];
#pragma unroll
  for (int i = 0; i < 4; ++i) {
    xr[i]     = *(const f32x4*)&xrow[sb8 + 32 * i];
    xr[4 + i] = *(const f32x4*)&xrow[SPB + sb8 + 32 * i];
  }
#pragma unroll
  for (int i = 0; i < 4; ++i)
#pragma unroll
    for (int e = 0; e < 4; ++e)
      xb32[swzc(sb8 + 32 * i + e, c0) >> 1] = pk2(xr[i][e], xr[4 + i][e]);
  __syncthreads();   // S0: X0 staged, Wq resident (full drain)

#pragma unroll
  for (int si = 0; si < 4; ++si) {
    const int sg = sbase + si * 128;

    // ---- A-frags for this sub-tile -> regs ----
    u16x8 afr[4];
#pragma unroll
    for (int ks = 0; ks < 4; ++ks)
      afr[ks] = *(const u16x8*)&xb[swzc(wv * 16 + lr, ks * 32 + lg * 8)];

    // ---- T14: issue next X sub-tile loads (consumed at loop tail) ----
    if (si < 3) {
      const float* xn = xrow + (si + 1) * 128;
#pragma unroll
      for (int i = 0; i < 4; ++i) {
        xr[i]     = *(const f32x4*)&xn[sb8 + 32 * i];
        xr[4 + i] = *(const f32x4*)&xn[SPB + sb8 + 32 * i];
      }
    }
    bar_lgkm();   // afr reads done by all waves; xb free for repack

    // ---- one conv: GEMM from wt, prefetch next W, repack, 256B stores ----
    auto conv = [&](int ci, const unsigned short* Wnext,
                    unsigned short* __restrict__ Y, bool last) {
      f32x4 acc[8];
#pragma unroll
      for (int of = 0; of < 8; ++of) {
        f32x4 z = {0.f, 0.f, 0.f, 0.f};
        acc[of] = z;
      }
#pragma unroll
      for (int ks = 0; ks < 4; ++ks) {
        const int k0 = ks * 32 + lg * 8;
#pragma unroll
        for (int of = 0; of < 8; ++of) {
          u16x8 wfr = *(const u16x8*)&wt[widx(of * 16 + lr, k0)];
          acc[of] = MFMA16(afr[ks], wfr, acc[of]);   // D[s][o] per lane
        }
      }
      bar_lgkm();   // all waves' wt reads done -> wt reusable
      if (Wnext) {
#pragma unroll
        for (int p = 0; p < 4; ++p)
          glds16(&Wnext[p * 4096 + go], &wt[p * 4096 + go]);
      }
      // epilogue: bias + cvt_pk -> b64 repack writes (s-major rows of xb)
#pragma unroll
      for (int of = 0; of < 8; ++of) {
        const float b = bias_lds[ci][of * 16 + lr];
        u32x2 pk;
        pk.x = pk2(acc[of][0] + b, acc[of][1] + b);
        pk.y = pk2(acc[of][2] + b, acc[of][3] + b);
        *(u32x2*)&xb[cbix(of * 16 + lr, wv * 16 + lg * 4)] = pk;
      }
      bar_lgkm();   // repack visible
      // readback: 4 rows x 256B contiguous per wave instruction
#pragma unroll
      for (int p = 0; p < 4; ++p) {
        const int row = p * 32 + (tid >> 4);
        const int sc  = (tid & 15) * 8;
        u16x8 v = *(const u16x8*)&xb[cbix(row, sc)];
        *(u16x8*)&Y[xoff + (size_t)row * SPB + sg + sc] = v;
      }
      // drain glds (next W resident) + readback ds reads; keep 4 stores live
      if (!last) bar_vm4_lgkm();
    };

    conv(0, Wbf + WTAB,     Yq, false);
    conv(1, Wbf + 2 * WTAB, Yk, false);
    conv(2, si < 3 ? Wbf : nullptr, Yv, si == 3);

    // ---- stage next sub-tile from prefetched regs ----
    if (si < 3) {
#pragma unroll
      for (int i = 0; i < 4; ++i)
#pragma unroll
        for (int e = 0; e < 4; ++e)
          xb32[swzc(sb8 + 32 * i + e, c0) >> 1] = pk2(xr[i][e], xr[4 + i][e]);
      bar_lgkm();   // staged; Wq already resident from conv2's bar
    }
  }
}

// ---------------------------------------------------------------------------
// K2: attention per (b,c,d) 64x64 slice (unchanged).
// ---------------------------------------------------------------------------
__global__ __launch_bounds__(256, 4) void attn64_kernel(
    const unsigned short* __restrict__ Q,
    const unsigned short* __restrict__ K,
    const unsigned short* __restrict__ V,
    unsigned short* __restrict__ O)
{
  __shared__ unsigned short qt[4096];   // Q^T[w][x]
  __shared__ unsigned short kt[4096];   // K^T[w][x]
  __shared__ unsigned short vt[4096];   // V^T[w][x]
  __shared__ unsigned short pbuf[4096]; // P rows (wave-private)

  const int tid  = threadIdx.x;
  const int wv   = tid >> 6;
  const int lane = tid & 63;
  const int lr   = lane & 15;
  const int lg   = lane >> 4;
  const int bid  = blockIdx.x;                       // 8192 = 8 * 1024
  const int bs   = ((bid & 7) << 10) | (bid >> 3);   // XCD-chunked
  const size_t base = (size_t)bs * 4096;

  {
    const int x0 = (tid >> 3) * 2;
    const int w0 = (tid & 7) * 8;
    const size_t ga = base + (size_t)x0 * 64 + w0;
    u16x8 qa = *(const u16x8*)&Q[ga], qb = *(const u16x8*)&Q[ga + 64];
    u16x8 ka = *(const u16x8*)&K[ga], kb = *(const u16x8*)&K[ga + 64];
    u16x8 va = *(const u16x8*)&V[ga], vb = *(const u16x8*)&V[ga + 64];
    unsigned int* qt32 = (unsigned int*)qt;
    unsigned int* kt32 = (unsigned int*)kt;
    unsigned int* vt32 = (unsigned int*)vt;
#pragma unroll
    for (int e = 0; e < 8; ++e) {
      const int idx = swat(w0 + e, x0) >> 1;
      qt32[idx] = (unsigned int)qa[e] | ((unsigned int)qb[e] << 16);
      kt32[idx] = (unsigned int)ka[e] | ((unsigned int)kb[e] << 16);
      vt32[idx] = (unsigned int)va[e] | ((unsigned int)vb[e] << 16);
    }
  }
  __syncthreads();

  f32x4 sacc[4];
#pragma unroll
  for (int nf = 0; nf < 4; ++nf) { f32x4 z = {0.f, 0.f, 0.f, 0.f}; sacc[nf] = z; }
#pragma unroll
  for (int ks = 0; ks < 2; ++ks) {
    const int k0 = ks * 32 + lg * 8;
    u16x8 a = *(const u16x8*)&qt[swat(wv * 16 + lr, k0)];
#pragma unroll
    for (int nf = 0; nf < 4; ++nf) {
      u16x8 bb = *(const u16x8*)&kt[swat(nf * 16 + lr, k0)];
      sacc[nf] = MFMA16(a, bb, sacc[nf]);
    }
  }

#pragma unroll
  for (int r = 0; r < 4; ++r) {
    float m = fmaxf(fmaxf(sacc[0][r], sacc[1][r]), fmaxf(sacc[2][r], sacc[3][r]));
    m = fmaxf(m, __shfl_xor(m, 1));
    m = fmaxf(m, __shfl_xor(m, 2));
    m = fmaxf(m, __shfl_xor(m, 4));
    m = fmaxf(m, __shfl_xor(m, 8));
    float sum = 0.f;
#pragma unroll
    for (int nf = 0; nf < 4; ++nf) {
      float p = __expf(sacc[nf][r] - m);
      sacc[nf][r] = p;
      sum += p;
    }
    sum += __shfl_xor(sum, 1);
    sum += __shfl_xor(sum, 2);
    sum += __shfl_xor(sum, 4);
    sum += __shfl_xor(sum, 8);
    const float inv = 1.f / sum;
    const int i = wv * 16 + lg * 4 + r;
#pragma unroll
    for (int nf = 0; nf < 4; ++nf)
      pbuf[pix(i, nf * 16 + lr)] = f2b(sacc[nf][r] * inv);
  }

  f32x4 oacc[4];
#pragma unroll
  for (int nf = 0; nf < 4; ++nf) { f32x4 z = {0.f, 0.f, 0.f, 0.f}; oacc[nf] = z; }
#pragma unroll
  for (int ks = 0; ks < 2; ++ks) {
    const int k0 = ks * 32 + lg * 8;
    u16x8 a = *(const u16x8*)&pbuf[pix(wv * 16 + lr, k0)];
#pragma unroll
    for (int nf = 0; nf < 4; ++nf) {
      u16x8 bb = *(const u16x8*)&vt[swat(nf * 16 + lr, k0)];
      oacc[nf] = MFMA16(bb, a, oacc[nf]);   // swapped args
    }
  }

  {
    const size_t ib = base + (size_t)(16 * wv + lr) * 64 + lg * 4;
#pragma unroll
    for (int nf = 0; nf < 4; ++nf) {
      u32x2 pk;
      pk.x = pk2(oacc[nf][0], oacc[nf][1]);
      pk.y = pk2(oacc[nf][2], oacc[nf][3]);
      *(u32x2*)&O[ib + nf * 16] = pk;
    }
  }
}

// ---------------------------------------------------------------------------
// K3: tail a1+relu -> a2 -> f (unchanged).
// ---------------------------------------------------------------------------
__global__ __launch_bounds__(256, 2) void tail_kernel(
    const unsigned short* __restrict__ Xb, const unsigned short* __restrict__ Wbf,
    const float* __restrict__ B1, const float* __restrict__ B2,
    const float* __restrict__ B3, float* __restrict__ OUT)
{
  __shared__ unsigned short wl[16384];   // W full (halved-table image)
  __shared__ unsigned short xc[16384];   // chain tile [s][c]
  __shared__ float bias_lds[3][128];

  const int tid  = threadIdx.x;
  const int wv   = tid >> 6;
  const int lane = tid & 63;
  const int lr   = lane & 15;
  const int lg   = lane >> 4;
  const int bx   = blockIdx.x;                      // 512 = 8 * 64
  const int bxs  = ((bx & 7) << 6) | (bx >> 3);     // XCD-chunked
  const int s0   = bxs * 128;
  const size_t xbase = (size_t)blockIdx.y * CCH * SPB;
  const int go = tid * 8;

#pragma unroll
  for (int p = 0; p < 8; ++p) glds16(&Wbf[p * 2048 + go], &wl[p * 2048 + go]);

  if (tid < 128) {
    bias_lds[0][tid] = B1[tid];
    bias_lds[1][tid] = B2[tid];
    bias_lds[2][tid] = B3[tid];
  }

  {
    const int cp = tid >> 2;
    const int sq = tid & 3;
    const unsigned short* xa = Xb + xbase + (size_t)(2 * cp) * SPB + s0 + sq * 32;
    const unsigned short* xb = xa + SPB;
    unsigned int* xc32 = (unsigned int*)xc;
#pragma unroll
    for (int i = 0; i < 4; ++i) {
      u16x8 a = *(const u16x8*)&xa[8 * i];
      u16x8 b = *(const u16x8*)&xb[8 * i];
#pragma unroll
      for (int e = 0; e < 8; ++e)
        xc32[swzc(sq * 32 + 8 * i + e, 2 * cp) >> 1] =
            (unsigned int)a[e] | ((unsigned int)b[e] << 16);
    }
  }
  __syncthreads();   // S1: stage + W1 resident

  u16x8 bfr[2][4];
#pragma unroll
  for (int nf = 0; nf < 2; ++nf)
#pragma unroll
    for (int ks = 0; ks < 4; ++ks)
      bfr[nf][ks] = *(const u16x8*)&xc[swzc(wv * 32 + nf * 16 + lr, ks * 32 + lg * 8)];

  f32x4 acc[8][2];
  auto gemm_std = [&]() {
#pragma unroll
    for (int mf = 0; mf < 8; ++mf)
#pragma unroll
      for (int nf = 0; nf < 2; ++nf) {
        f32x4 z = {0.f, 0.f, 0.f, 0.f};
        acc[mf][nf] = z;
      }
#pragma unroll
    for (int ks = 0; ks < 4; ++ks) {
      const int k0 = ks * 32 + lg * 8;
#pragma unroll
      for (int mf = 0; mf < 8; ++mf) {
        u16x8 afr = *(const u16x8*)&wl[widx(mf * 16 + lr, k0)];
        acc[mf][0] = MFMA16(afr, bfr[0][ks], acc[mf][0]);
        acc[mf][1] = MFMA16(afr, bfr[1][ks], acc[mf][1]);
      }
    }
  };

  auto epi_chain = [&](int ci, bool relu) {
#pragma unroll
    for (int mf = 0; mf < 8; ++mf)
#pragma unroll
      for (int nf = 0; nf < 2; ++nf) {
        const int s = wv * 32 + nf * 16 + lr;
        const int cc = mf * 16 + lg * 4;
        f32x4 bb = *(const f32x4*)&bias_lds[ci][cc];
        float v0 = acc[mf][nf][0] + bb[0];
        float v1 = acc[mf][nf][1] + bb[1];
        float v2 = acc[mf][nf][2] + bb[2];
        float v3 = acc[mf][nf][3] + bb[3];
        if (relu) {
          v0 = fmaxf(v0, 0.f); v1 = fmaxf(v1, 0.f);
          v2 = fmaxf(v2, 0.f); v3 = fmaxf(v3, 0.f);
        }
        u32x2 pk;
        pk.x = pk2(v0, v1);
        pk.y = pk2(v2, v3);
        *(u32x2*)&xc[swzc(s, cc)] = pk;
      }
#pragma unroll
    for (int nf = 0; nf < 2; ++nf)
#pragma unroll
      for (int ks = 0; ks < 4; ++ks)
        bfr[nf][ks] = *(const u16x8*)&xc[swzc(wv * 32 + nf * 16 + lr, ks * 32 + lg * 8)];
  };

#pragma unroll
  for (int j = 0; j < 2; ++j) {
    gemm_std();
    bar_lgkm();
    const unsigned short* Wn = Wbf + (size_t)(j + 1) * WTAB;
#pragma unroll
    for (int p = 0; p < 8; ++p) glds16(&Wn[p * 2048 + go], &wl[p * 2048 + go]);
    epi_chain(j, j == 0);
    bar_vm0();
  }

  {
    f32x4 acc3[2][8];
#pragma unroll
    for (int sf = 0; sf < 2; ++sf)
#pragma unroll
      for (int of = 0; of < 8; ++of) {
        f32x4 z = {0.f, 0.f, 0.f, 0.f};
        acc3[sf][of] = z;
      }
#pragma unroll
    for (int ks = 0; ks < 4; ++ks) {
      const int k0 = ks * 32 + lg * 8;
#pragma unroll
      for (int of = 0; of < 8; ++of) {
        u16x8 wfr = *(const u16x8*)&wl[widx(of * 16 + lr, k0)];
        acc3[0][of] = MFMA16(bfr[0][ks], wfr, acc3[0][of]);
        acc3[1][of] = MFMA16(bfr[1][ks], wfr, acc3[1][of]);
      }
    }
    const int sb = s0 + wv * 32 + lg * 4;
#pragma unroll
    for (int sf = 0; sf < 2; ++sf)
#pragma unroll
      for (int of = 0; of < 8; ++of) {
        const float b = bias_lds[2][of * 16 + lr];
        f32x4 v = acc3[sf][of];
        v[0] += b; v[1] += b; v[2] += b; v[3] += b;
        *(f32x4*)&OUT[xbase + (size_t)(of * 16 + lr) * SPB + sb + sf * 16] = v;
      }
  }
}

extern "C" void kernel_launch(void* const* d_in, const int* in_sizes, int n_in,
                              void* d_out, int out_size, void* d_ws, size_t ws_size,
                              hipStream_t stream) {
  const float* x   = (const float*)d_in[0];
  const float* Wq  = (const float*)d_in[1];  const float* bq  = (const float*)d_in[2];
  const float* Wk  = (const float*)d_in[3];  const float* bk  = (const float*)d_in[4];
  const float* Wv  = (const float*)d_in[5];  const float* bv  = (const float*)d_in[6];
  const float* Wa1 = (const float*)d_in[7];  const float* ba1 = (const float*)d_in[8];
  const float* Wa2 = (const float*)d_in[9];  const float* ba2 = (const float*)d_in[10];
  const float* Wf  = (const float*)d_in[11]; const float* bf_ = (const float*)d_in[12];

  // ws layout: q (67.1MB) then 6 bf16 weight tables (192KB).
  unsigned short* qb  = (unsigned short*)d_ws;
  unsigned short* wbf = qb + (size_t)NBATCH * CCH * SPB;
  // k,v packed into d_out (dead before final f32 write).
  unsigned short* kb = (unsigned short*)d_out;
  unsigned short* vb = kb + (size_t)NBATCH * CCH * SPB;

  prep_w_kernel<<<6, 256, 0, stream>>>(Wq, Wk, Wv, Wa1, Wa2, Wf, wbf);

  qkv_kernel<<<512, 512, 0, stream>>>(x, wbf, bq, bk, bv, qb, kb, vb);

  attn64_kernel<<<NBATCH * CCH * 16, 256, 0, stream>>>(qb, kb, vb, qb);

  tail_kernel<<<dim3(SPB / 128, NBATCH), 256, 0, stream>>>(
      qb, wbf + (size_t)3 * WTAB, ba1, ba2, bf_, (float*)d_out);
}

// Round 10
// 186.859 us; speedup vs baseline: 1.5790x; 1.0262x over previous
//
#include <hip/hip_runtime.h>

// SelfAttention3d: B=4, C=128, D=16, H=W=64.
//   K0 prep  : 6 weight mats f32 -> bf16, pre-swizzled halved tables in ws
//   K1 qkv   : 512-s strip/WG, W tables resident (96KB, 1 WG/CU), 3 convs
//              software-pipelined per sub-tile: GEMM_k ∥ readback_q etc.
//              v-conv stores direct from regs (no repack). XCD swizzle.
//   K2 attn  : per (b,c,d) 64x64; PV swapped -> direct b64 O stores
//   K3 tail  : a1+relu -> a2 (LDS chain) -> f swapped -> f32x4 stores

#define CCH 128
#define SPB 65536      // per-batch spatial = D*H*W
#define NBATCH 4
#define WTAB 16384     // elements per 128x128 weight table

typedef float f32x4 __attribute__((ext_vector_type(4)));
typedef __bf16 bf16x8 __attribute__((ext_vector_type(8)));
typedef short s16x8 __attribute__((ext_vector_type(8)));
typedef unsigned short u16x8 __attribute__((ext_vector_type(8)));
typedef unsigned short u16x4 __attribute__((ext_vector_type(4)));
typedef unsigned int u32x2 __attribute__((ext_vector_type(2)));

// ---- MFMA wrapper: robust to builtin signature (v8i16 vs v8bf16) ----
template <typename T>
static __device__ __forceinline__ auto mfma_try(T a, T b, f32x4 c, int)
    -> decltype(__builtin_amdgcn_mfma_f32_16x16x32_bf16(a, b, c, 0, 0, 0)) {
  return __builtin_amdgcn_mfma_f32_16x16x32_bf16(a, b, c, 0, 0, 0);
}
template <typename T>
static __device__ __forceinline__ f32x4 mfma_try(T a, T b, f32x4 c, long) {
  return __builtin_amdgcn_mfma_f32_16x16x32_bf16(
      __builtin_bit_cast(bf16x8, a), __builtin_bit_cast(bf16x8, b), c, 0, 0, 0);
}
static __device__ __forceinline__ f32x4 MFMA16(u16x8 a, u16x8 b, f32x4 c) {
  return mfma_try(__builtin_bit_cast(s16x8, a), __builtin_bit_cast(s16x8, b), c, 0);
}

static __device__ __forceinline__ unsigned short f2b(float f) {
  return __builtin_bit_cast(unsigned short, (__bf16)f);
}
static __device__ __forceinline__ unsigned int pk2(float a, float b) {
  return (unsigned int)f2b(a) | ((unsigned int)f2b(b) << 16);
}

// async global->LDS, 16B per lane (linear dest, pre-swizzled source tables)
static __device__ __forceinline__ void glds16(const unsigned short* g,
                                              unsigned short* l) {
  __builtin_amdgcn_global_load_lds(
      (const __attribute__((address_space(1))) unsigned int*)g,
      (__attribute__((address_space(3))) unsigned int*)l, 16, 0, 0);
}

// lgkm-only barrier: LDS ordering without draining stores (T4 pattern)
static __device__ __forceinline__ void bar_lgkm() {
  asm volatile("s_waitcnt lgkmcnt(0)" ::: "memory");
  __builtin_amdgcn_sched_barrier(0);
  __builtin_amdgcn_s_barrier();
  __builtin_amdgcn_sched_barrier(0);
}
static __device__ __forceinline__ void bar_vm0() {
  asm volatile("s_waitcnt vmcnt(0)" ::: "memory");
  __builtin_amdgcn_sched_barrier(0);
  __builtin_amdgcn_s_barrier();
  __builtin_amdgcn_sched_barrier(0);
}

// --- swizzles (element index), bijective per row ---
static __device__ __forceinline__ int swzc(int r, int c) {   // 128-col u16 tile
  int slot = ((c >> 3) ^ (r & 7) ^ ((r >> 3) & 15)) & 15;
  return r * 128 + slot * 8 + (c & 7);
}
static __device__ __forceinline__ int widx(int r, int c) {   // halved W table
  return (r & 64) * 128 + swzc(r & 63, c);
}
// C repack tile [o][s] u16 (qkv): b64 epilogue writes + 256B readback rows.
static __device__ __forceinline__ int cbix(int o, int s) {
  int slot = ((s >> 3) ^ (o & 15)) & 15;
  return o * 128 + slot * 8 + (s & 7);
}
static __device__ __forceinline__ int swat(int w, int x) {   // 64-col attn tile
  int slot = ((x >> 3) ^ (w & 7) ^ ((w >> 3) & 7)) & 7;
  return w * 64 + slot * 8 + (x & 7);
}
static __device__ __forceinline__ int pix(int i, int j) {    // attn P tile
  int slot = ((j >> 3) ^ (((i >> 2) & 3) << 1)) & 7;
  return i * 64 + slot * 8 + (j & 7);
}

// ---------------------------------------------------------------------------
// K0: weights f32 -> bf16 into halved swizzled tables (rows 0-63 | 64-127).
// ---------------------------------------------------------------------------
__global__ __launch_bounds__(256) void prep_w_kernel(
    const float* __restrict__ Wq, const float* __restrict__ Wk,
    const float* __restrict__ Wv, const float* __restrict__ W1,
    const float* __restrict__ W2, const float* __restrict__ W3,
    unsigned short* __restrict__ out)
{
  const float* Ws[6] = {Wq, Wk, Wv, W1, W2, W3};
  const float* W = Ws[blockIdx.x];
  unsigned short* o = out + (size_t)blockIdx.x * WTAB;
  const int tid = threadIdx.x;
#pragma unroll
  for (int p = 0; p < 16; ++p) {
    const int base = p * 1024 + tid * 4;
    const int m = base >> 7;
    const int c0 = base & 127;
    f32x4 v = *(const f32x4*)&W[base];
    u16x4 u;
#pragma unroll
    for (int e = 0; e < 4; ++e) u[e] = f2b(v[e]);
    *(u16x4*)&o[widx(m, c0)] = u;
  }
}

// ---------------------------------------------------------------------------
// K1: fused QKV. 512 WGs x 512 thr, 512-s strip/WG. W resident (96KB).
// Per 128-s sub-tile, the 3 convs are software-pipelined so each barrier-free
// region mixes MFMA with LDS readback / global stores.
// ---------------------------------------------------------------------------
__global__ __launch_bounds__(512, 2) void qkv_kernel(
    const float* __restrict__ X, const unsigned short* __restrict__ Wbf,
    const float* __restrict__ Bq, const float* __restrict__ Bk,
    const float* __restrict__ Bv,
    unsigned short* __restrict__ Yq, unsigned short* __restrict__ Yk,
    unsigned short* __restrict__ Yv)
{
  __shared__ unsigned short wt[3 * WTAB];  // 96KB: Wq,Wk,Wv swizzled images
  __shared__ unsigned short xb[WTAB];      // 32KB: X^T stage / C repack

  const int tid  = threadIdx.x;
  const int wv   = tid >> 6;
  const int lane = tid & 63;
  const int lr   = lane & 15;
  const int lg   = lane >> 4;
  // XCD-chunked swizzle: 512 blocks -> each XCD gets 64 contiguous strips
  const int lin  = blockIdx.x;
  const int swz  = ((lin & 7) << 6) | (lin >> 3);
  const int sbase = (swz & 127) * 512;
  const size_t xoff = (size_t)(swz >> 7) * CCH * SPB;
  const int go = tid * 8;

  // ---- issue all W glds up front (12 x 16B/thread; drained at S0) ----
#pragma unroll
  for (int t = 0; t < 3; ++t)
#pragma unroll
    for (int p = 0; p < 4; ++p)
      glds16(&Wbf[t * WTAB + p * 4096 + go], &wt[t * WTAB + p * 4096 + go]);

  // ---- bias -> regs (o = of*16+lr per lane) ----
  float bq_v[8], bk_v[8], bv_v[8];
#pragma unroll
  for (int of = 0; of < 8; ++of) {
    bq_v[of] = Bq[of * 16 + lr];
    bk_v[of] = Bk[of * 16 + lr];
    bv_v[of] = Bv[of * 16 + lr];
  }

  // staging geometry: thread owns c-pair (c0,c0+1), 4x4 s-chunks
  const int c0  = (tid >> 3) * 2;
  const int sb8 = (tid & 7) * 4;
  const float* xrow = X + xoff + (size_t)c0 * SPB + sbase;
  unsigned int* xb32 = (unsigned int*)xb;

  f32x4 xr[8];
#pragma unroll
  for (int i = 0; i < 4; ++i) {
    xr[i]     = *(const f32x4*)&xrow[sb8 + 32 * i];
    xr[4 + i] = *(const f32x4*)&xrow[SPB + sb8 + 32 * i];
  }
#pragma unroll
  for (int i = 0; i < 4; ++i)
#pragma unroll
    for (int e = 0; e < 4; ++e)
      xb32[swzc(sb8 + 32 * i + e, c0) >> 1] = pk2(xr[i][e], xr[4 + i][e]);
  __syncthreads();   // S0: X0 staged, all W resident (full vm drain)

#pragma unroll
  for (int si = 0; si < 4; ++si) {
    const int sg = sbase + si * 128;

    // ---- R0: prefetch next X (T14) + A-frag reads ----
    if (si < 3) {
      const float* xn = xrow + (si + 1) * 128;
#pragma unroll
      for (int i = 0; i < 4; ++i) {
        xr[i]     = *(const f32x4*)&xn[sb8 + 32 * i];
        xr[4 + i] = *(const f32x4*)&xn[SPB + sb8 + 32 * i];
      }
    }
    u16x8 afr[4];
#pragma unroll
    for (int ks = 0; ks < 4; ++ks)
      afr[ks] = *(const u16x8*)&xb[swzc(wv * 16 + lr, ks * 32 + lg * 8)];
    bar_lgkm();   // afr reads done by all waves; xb free

    // ---- R1: GEMM_q ∥ repack_q ----
    f32x4 accq[8];
#pragma unroll
    for (int of = 0; of < 8; ++of) { f32x4 z = {0.f,0.f,0.f,0.f}; accq[of] = z; }
#pragma unroll
    for (int ks = 0; ks < 4; ++ks) {
      const int k0 = ks * 32 + lg * 8;
#pragma unroll
      for (int of = 0; of < 8; ++of)
        accq[of] = MFMA16(afr[ks], *(const u16x8*)&wt[widx(of*16+lr, k0)], accq[of]);
    }
#pragma unroll
    for (int of = 0; of < 8; ++of) {
      const float b = bq_v[of];
      u32x2 pk;
      pk.x = pk2(accq[of][0] + b, accq[of][1] + b);
      pk.y = pk2(accq[of][2] + b, accq[of][3] + b);
      *(u32x2*)&xb[cbix(of * 16 + lr, wv * 16 + lg * 4)] = pk;
    }
    bar_lgkm();   // repack_q visible

    // ---- R2: GEMM_k ∥ readback_q + store_q ----
    f32x4 acck[8];
#pragma unroll
    for (int of = 0; of < 8; ++of) { f32x4 z = {0.f,0.f,0.f,0.f}; acck[of] = z; }
#pragma unroll
    for (int ks = 0; ks < 4; ++ks) {
      const int k0 = ks * 32 + lg * 8;
#pragma unroll
      for (int of = 0; of < 8; ++of)
        acck[of] = MFMA16(afr[ks], *(const u16x8*)&wt[WTAB + widx(of*16+lr, k0)], acck[of]);
    }
#pragma unroll
    for (int p = 0; p < 4; ++p) {
      const int row = p * 32 + (tid >> 4);
      const int sc  = (tid & 15) * 8;
      u16x8 v = *(const u16x8*)&xb[cbix(row, sc)];
      *(u16x8*)&Yq[xoff + (size_t)row * SPB + sg + sc] = v;
    }
    bar_lgkm();   // readback_q ds reads done; xb free (stores in flight)

    // ---- R3: GEMM_v ∥ repack_k ----
    f32x4 accv[8];
#pragma unroll
    for (int of = 0; of < 8; ++of) { f32x4 z = {0.f,0.f,0.f,0.f}; accv[of] = z; }
#pragma unroll
    for (int ks = 0; ks < 4; ++ks) {
      const int k0 = ks * 32 + lg * 8;
#pragma unroll
      for (int of = 0; of < 8; ++of)
        accv[of] = MFMA16(afr[ks], *(const u16x8*)&wt[2*WTAB + widx(of*16+lr, k0)], accv[of]);
    }
#pragma unroll
    for (int of = 0; of < 8; ++of) {
      const float b = bk_v[of];
      u32x2 pk;
      pk.x = pk2(acck[of][0] + b, acck[of][1] + b);
      pk.y = pk2(acck[of][2] + b, acck[of][3] + b);
      *(u32x2*)&xb[cbix(of * 16 + lr, wv * 16 + lg * 4)] = pk;
    }
    bar_lgkm();   // repack_k visible

    // ---- R4: readback_k + store_k ∥ direct store_v ----
#pragma unroll
    for (int p = 0; p < 4; ++p) {
      const int row = p * 32 + (tid >> 4);
      const int sc  = (tid & 15) * 8;
      u16x8 v = *(const u16x8*)&xb[cbix(row, sc)];
      *(u16x8*)&Yk[xoff + (size_t)row * SPB + sg + sc] = v;
    }
    {
      const int sl = sg + wv * 16 + lg * 4;
#pragma unroll
      for (int of = 0; of < 8; ++of) {
        const float b = bv_v[of];
        u32x2 pk;
        pk.x = pk2(accv[of][0] + b, accv[of][1] + b);
        pk.y = pk2(accv[of][2] + b, accv[of][3] + b);
        *(u32x2*)&Yv[xoff + (size_t)(of * 16 + lr) * SPB + sl] = pk;
      }
    }

    // ---- R5: stage next sub-tile from prefetched regs ----
    if (si < 3) {
      bar_lgkm();   // readback_k ds reads done; xb free
#pragma unroll
      for (int i = 0; i < 4; ++i)
#pragma unroll
        for (int e = 0; e < 4; ++e)
          xb32[swzc(sb8 + 32 * i + e, c0) >> 1] = pk2(xr[i][e], xr[4 + i][e]);
      bar_lgkm();   // staged
    }
  }
}

// ---------------------------------------------------------------------------
// K2: attention per (b,c,d) 64x64 slice (unchanged).
// ---------------------------------------------------------------------------
__global__ __launch_bounds__(256, 4) void attn64_kernel(
    const unsigned short* __restrict__ Q,
    const unsigned short* __restrict__ K,
    const unsigned short* __restrict__ V,
    unsigned short* __restrict__ O)
{
  __shared__ unsigned short qt[4096];   // Q^T[w][x]
  __shared__ unsigned short kt[4096];   // K^T[w][x]
  __shared__ unsigned short vt[4096];   // V^T[w][x]
  __shared__ unsigned short pbuf[4096]; // P rows (wave-private)

  const int tid  = threadIdx.x;
  const int wv   = tid >> 6;
  const int lane = tid & 63;
  const int lr   = lane & 15;
  const int lg   = lane >> 4;
  const int bid  = blockIdx.x;                       // 8192 = 8 * 1024
  const int bs   = ((bid & 7) << 10) | (bid >> 3);   // XCD-chunked
  const size_t base = (size_t)bs * 4096;

  {
    const int x0 = (tid >> 3) * 2;
    const int w0 = (tid & 7) * 8;
    const size_t ga = base + (size_t)x0 * 64 + w0;
    u16x8 qa = *(const u16x8*)&Q[ga], qb = *(const u16x8*)&Q[ga + 64];
    u16x8 ka = *(const u16x8*)&K[ga], kb = *(const u16x8*)&K[ga + 64];
    u16x8 va = *(const u16x8*)&V[ga], vb = *(const u16x8*)&V[ga + 64];
    unsigned int* qt32 = (unsigned int*)qt;
    unsigned int* kt32 = (unsigned int*)kt;
    unsigned int* vt32 = (unsigned int*)vt;
#pragma unroll
    for (int e = 0; e < 8; ++e) {
      const int idx = swat(w0 + e, x0) >> 1;
      qt32[idx] = (unsigned int)qa[e] | ((unsigned int)qb[e] << 16);
      kt32[idx] = (unsigned int)ka[e] | ((unsigned int)kb[e] << 16);
      vt32[idx] = (unsigned int)va[e] | ((unsigned int)vb[e] << 16);
    }
  }
  __syncthreads();

  f32x4 sacc[4];
#pragma unroll
  for (int nf = 0; nf < 4; ++nf) { f32x4 z = {0.f, 0.f, 0.f, 0.f}; sacc[nf] = z; }
#pragma unroll
  for (int ks = 0; ks < 2; ++ks) {
    const int k0 = ks * 32 + lg * 8;
    u16x8 a = *(const u16x8*)&qt[swat(wv * 16 + lr, k0)];
#pragma unroll
    for (int nf = 0; nf < 4; ++nf) {
      u16x8 bb = *(const u16x8*)&kt[swat(nf * 16 + lr, k0)];
      sacc[nf] = MFMA16(a, bb, sacc[nf]);
    }
  }

#pragma unroll
  for (int r = 0; r < 4; ++r) {
    float m = fmaxf(fmaxf(sacc[0][r], sacc[1][r]), fmaxf(sacc[2][r], sacc[3][r]));
    m = fmaxf(m, __shfl_xor(m, 1));
    m = fmaxf(m, __shfl_xor(m, 2));
    m = fmaxf(m, __shfl_xor(m, 4));
    m = fmaxf(m, __shfl_xor(m, 8));
    float sum = 0.f;
#pragma unroll
    for (int nf = 0; nf < 4; ++nf) {
      float p = __expf(sacc[nf][r] - m);
      sacc[nf][r] = p;
      sum += p;
    }
    sum += __shfl_xor(sum, 1);
    sum += __shfl_xor(sum, 2);
    sum += __shfl_xor(sum, 4);
    sum += __shfl_xor(sum, 8);
    const float inv = 1.f / sum;
    const int i = wv * 16 + lg * 4 + r;
#pragma unroll
    for (int nf = 0; nf < 4; ++nf)
      pbuf[pix(i, nf * 16 + lr)] = f2b(sacc[nf][r] * inv);
  }

  f32x4 oacc[4];
#pragma unroll
  for (int nf = 0; nf < 4; ++nf) { f32x4 z = {0.f, 0.f, 0.f, 0.f}; oacc[nf] = z; }
#pragma unroll
  for (int ks = 0; ks < 2; ++ks) {
    const int k0 = ks * 32 + lg * 8;
    u16x8 a = *(const u16x8*)&pbuf[pix(wv * 16 + lr, k0)];
#pragma unroll
    for (int nf = 0; nf < 4; ++nf) {
      u16x8 bb = *(const u16x8*)&vt[swat(nf * 16 + lr, k0)];
      oacc[nf] = MFMA16(bb, a, oacc[nf]);   // swapped args
    }
  }

  {
    const size_t ib = base + (size_t)(16 * wv + lr) * 64 + lg * 4;
#pragma unroll
    for (int nf = 0; nf < 4; ++nf) {
      u32x2 pk;
      pk.x = pk2(oacc[nf][0], oacc[nf][1]);
      pk.y = pk2(oacc[nf][2], oacc[nf][3]);
      *(u32x2*)&O[ib + nf * 16] = pk;
    }
  }
}

// ---------------------------------------------------------------------------
// K3: tail a1+relu -> a2 -> f (unchanged).
// ---------------------------------------------------------------------------
__global__ __launch_bounds__(256, 2) void tail_kernel(
    const unsigned short* __restrict__ Xb, const unsigned short* __restrict__ Wbf,
    const float* __restrict__ B1, const float* __restrict__ B2,
    const float* __restrict__ B3, float* __restrict__ OUT)
{
  __shared__ unsigned short wl[16384];   // W full (halved-table image)
  __shared__ unsigned short xc[16384];   // chain tile [s][c]
  __shared__ float bias_lds[3][128];

  const int tid  = threadIdx.x;
  const int wv   = tid >> 6;
  const int lane = tid & 63;
  const int lr   = lane & 15;
  const int lg   = lane >> 4;
  const int bx   = blockIdx.x;                      // 512 = 8 * 64
  const int bxs  = ((bx & 7) << 6) | (bx >> 3);     // XCD-chunked
  const int s0   = bxs * 128;
  const size_t xbase = (size_t)blockIdx.y * CCH * SPB;
  const int go = tid * 8;

#pragma unroll
  for (int p = 0; p < 8; ++p) glds16(&Wbf[p * 2048 + go], &wl[p * 2048 + go]);

  if (tid < 128) {
    bias_lds[0][tid] = B1[tid];
    bias_lds[1][tid] = B2[tid];
    bias_lds[2][tid] = B3[tid];
  }

  {
    const int cp = tid >> 2;
    const int sq = tid & 3;
    const unsigned short* xa = Xb + xbase + (size_t)(2 * cp) * SPB + s0 + sq * 32;
    const unsigned short* xb = xa + SPB;
    unsigned int* xc32 = (unsigned int*)xc;
#pragma unroll
    for (int i = 0; i < 4; ++i) {
      u16x8 a = *(const u16x8*)&xa[8 * i];
      u16x8 b = *(const u16x8*)&xb[8 * i];
#pragma unroll
      for (int e = 0; e < 8; ++e)
        xc32[swzc(sq * 32 + 8 * i + e, 2 * cp) >> 1] =
            (unsigned int)a[e] | ((unsigned int)b[e] << 16);
    }
  }
  __syncthreads();   // S1: stage + W1 resident

  u16x8 bfr[2][4];
#pragma unroll
  for (int nf = 0; nf < 2; ++nf)
#pragma unroll
    for (int ks = 0; ks < 4; ++ks)
      bfr[nf][ks] = *(const u16x8*)&xc[swzc(wv * 32 + nf * 16 + lr, ks * 32 + lg * 8)];

  f32x4 acc[8][2];
  auto gemm_std = [&]() {
#pragma unroll
    for (int mf = 0; mf < 8; ++mf)
#pragma unroll
      for (int nf = 0; nf < 2; ++nf) {
        f32x4 z = {0.f, 0.f, 0.f, 0.f};
        acc[mf][nf] = z;
      }
#pragma unroll
    for (int ks = 0; ks < 4; ++ks) {
      const int k0 = ks * 32 + lg * 8;
#pragma unroll
      for (int mf = 0; mf < 8; ++mf) {
        u16x8 afr = *(const u16x8*)&wl[widx(mf * 16 + lr, k0)];
        acc[mf][0] = MFMA16(afr, bfr[0][ks], acc[mf][0]);
        acc[mf][1] = MFMA16(afr, bfr[1][ks], acc[mf][1]);
      }
    }
  };

  auto epi_chain = [&](int ci, bool relu) {
#pragma unroll
    for (int mf = 0; mf < 8; ++mf)
#pragma unroll
      for (int nf = 0; nf < 2; ++nf) {
        const int s = wv * 32 + nf * 16 + lr;
        const int cc = mf * 16 + lg * 4;
        f32x4 bb = *(const f32x4*)&bias_lds[ci][cc];
        float v0 = acc[mf][nf][0] + bb[0];
        float v1 = acc[mf][nf][1] + bb[1];
        float v2 = acc[mf][nf][2] + bb[2];
        float v3 = acc[mf][nf][3] + bb[3];
        if (relu) {
          v0 = fmaxf(v0, 0.f); v1 = fmaxf(v1, 0.f);
          v2 = fmaxf(v2, 0.f); v3 = fmaxf(v3, 0.f);
        }
        u32x2 pk;
        pk.x = pk2(v0, v1);
        pk.y = pk2(v2, v3);
        *(u32x2*)&xc[swzc(s, cc)] = pk;
      }
#pragma unroll
    for (int nf = 0; nf < 2; ++nf)
#pragma unroll
      for (int ks = 0; ks < 4; ++ks)
        bfr[nf][ks] = *(const u16x8*)&xc[swzc(wv * 32 + nf * 16 + lr, ks * 32 + lg * 8)];
  };

#pragma unroll
  for (int j = 0; j < 2; ++j) {
    gemm_std();
    bar_lgkm();
    const unsigned short* Wn = Wbf + (size_t)(j + 1) * WTAB;
#pragma unroll
    for (int p = 0; p < 8; ++p) glds16(&Wn[p * 2048 + go], &wl[p * 2048 + go]);
    epi_chain(j, j == 0);
    bar_vm0();
  }

  {
    f32x4 acc3[2][8];
#pragma unroll
    for (int sf = 0; sf < 2; ++sf)
#pragma unroll
      for (int of = 0; of < 8; ++of) {
        f32x4 z = {0.f, 0.f, 0.f, 0.f};
        acc3[sf][of] = z;
      }
#pragma unroll
    for (int ks = 0; ks < 4; ++ks) {
      const int k0 = ks * 32 + lg * 8;
#pragma unroll
      for (int of = 0; of < 8; ++of) {
        u16x8 wfr = *(const u16x8*)&wl[widx(of * 16 + lr, k0)];
        acc3[0][of] = MFMA16(bfr[0][ks], wfr, acc3[0][of]);
        acc3[1][of] = MFMA16(bfr[1][ks], wfr, acc3[1][of]);
      }
    }
    const int sb = s0 + wv * 32 + lg * 4;
#pragma unroll
    for (int sf = 0; sf < 2; ++sf)
#pragma unroll
      for (int of = 0; of < 8; ++of) {
        const float b = bias_lds[2][of * 16 + lr];
        f32x4 v = acc3[sf][of];
        v[0] += b; v[1] += b; v[2] += b; v[3] += b;
        *(f32x4*)&OUT[xbase + (size_t)(of * 16 + lr) * SPB + sb + sf * 16] = v;
      }
  }
}

extern "C" void kernel_launch(void* const* d_in, const int* in_sizes, int n_in,
                              void* d_out, int out_size, void* d_ws, size_t ws_size,
                              hipStream_t stream) {
  const float* x   = (const float*)d_in[0];
  const float* Wq  = (const float*)d_in[1];  const float* bq  = (const float*)d_in[2];
  const float* Wk  = (const float*)d_in[3];  const float* bk  = (const float*)d_in[4];
  const float* Wv  = (const float*)d_in[5];  const float* bv  = (const float*)d_in[6];
  const float* Wa1 = (const float*)d_in[7];  const float* ba1 = (const float*)d_in[8];
  const float* Wa2 = (const float*)d_in[9];  const float* ba2 = (const float*)d_in[10];
  const float* Wf  = (const float*)d_in[11]; const float* bf_ = (const float*)d_in[12];

  // ws layout: q (67.1MB) then 6 bf16 weight tables (192KB).
  unsigned short* qb  = (unsigned short*)d_ws;
  unsigned short* wbf = qb + (size_t)NBATCH * CCH * SPB;
  // k,v packed into d_out (dead before final f32 write).
  unsigned short* kb = (unsigned short*)d_out;
  unsigned short* vb = kb + (size_t)NBATCH * CCH * SPB;

  prep_w_kernel<<<6, 256, 0, stream>>>(Wq, Wk, Wv, Wa1, Wa2, Wf, wbf);

  qkv_kernel<<<512, 512, 0, stream>>>(x, wbf, bq, bk, bv, qb, kb, vb);

  attn64_kernel<<<NBATCH * CCH * 16, 256, 0, stream>>>(qb, kb, vb, qb);

  tail_kernel<<<dim3(SPB / 128, NBATCH), 256, 0, stream>>>(
      qb, wbf + (size_t)3 * WTAB, ba1, ba2, bf_, (float*)d_out);
}

// Round 11
// 184.353 us; speedup vs baseline: 1.6004x; 1.0136x over previous
//
#include <hip/hip_runtime.h>

// SelfAttention3d: B=4, C=128, D=16, H=W=64.
//   K0 prep  : 6 weight mats f32 -> bf16, pre-swizzled halved tables in ws
//   K1 qkv   : 512-s strip/WG, W resident (96KB) + dual C-buffers (xb,cb):
//              every readback/store overlaps a GEMM; all stores 256B bursts.
//   K2 attn  : per (b,c,d) 64x64; PV swapped -> direct b64 O stores
//   K3 tail  : a1+relu -> a2 (LDS chain) -> f; f32 out via swizzled LDS
//              chunks -> 512B contiguous bursts.

#define CCH 128
#define SPB 65536      // per-batch spatial = D*H*W
#define NBATCH 4
#define WTAB 16384     // elements per 128x128 weight table

typedef float f32x4 __attribute__((ext_vector_type(4)));
typedef __bf16 bf16x8 __attribute__((ext_vector_type(8)));
typedef short s16x8 __attribute__((ext_vector_type(8)));
typedef unsigned short u16x8 __attribute__((ext_vector_type(8)));
typedef unsigned short u16x4 __attribute__((ext_vector_type(4)));
typedef unsigned int u32x2 __attribute__((ext_vector_type(2)));

// ---- MFMA wrapper: robust to builtin signature (v8i16 vs v8bf16) ----
template <typename T>
static __device__ __forceinline__ auto mfma_try(T a, T b, f32x4 c, int)
    -> decltype(__builtin_amdgcn_mfma_f32_16x16x32_bf16(a, b, c, 0, 0, 0)) {
  return __builtin_amdgcn_mfma_f32_16x16x32_bf16(a, b, c, 0, 0, 0);
}
template <typename T>
static __device__ __forceinline__ f32x4 mfma_try(T a, T b, f32x4 c, long) {
  return __builtin_amdgcn_mfma_f32_16x16x32_bf16(
      __builtin_bit_cast(bf16x8, a), __builtin_bit_cast(bf16x8, b), c, 0, 0, 0);
}
static __device__ __forceinline__ f32x4 MFMA16(u16x8 a, u16x8 b, f32x4 c) {
  return mfma_try(__builtin_bit_cast(s16x8, a), __builtin_bit_cast(s16x8, b), c, 0);
}

static __device__ __forceinline__ unsigned short f2b(float f) {
  return __builtin_bit_cast(unsigned short, (__bf16)f);
}
static __device__ __forceinline__ unsigned int pk2(float a, float b) {
  return (unsigned int)f2b(a) | ((unsigned int)f2b(b) << 16);
}

// async global->LDS, 16B per lane (linear dest, pre-swizzled source tables)
static __device__ __forceinline__ void glds16(const unsigned short* g,
                                              unsigned short* l) {
  __builtin_amdgcn_global_load_lds(
      (const __attribute__((address_space(1))) unsigned int*)g,
      (__attribute__((address_space(3))) unsigned int*)l, 16, 0, 0);
}

// lgkm-only barrier: LDS ordering without draining stores (T4 pattern)
static __device__ __forceinline__ void bar_lgkm() {
  asm volatile("s_waitcnt lgkmcnt(0)" ::: "memory");
  __builtin_amdgcn_sched_barrier(0);
  __builtin_amdgcn_s_barrier();
  __builtin_amdgcn_sched_barrier(0);
}
static __device__ __forceinline__ void bar_vm0() {
  asm volatile("s_waitcnt vmcnt(0)" ::: "memory");
  __builtin_amdgcn_sched_barrier(0);
  __builtin_amdgcn_s_barrier();
  __builtin_amdgcn_sched_barrier(0);
}

// --- swizzles (element index), bijective per row ---
static __device__ __forceinline__ int swzc(int r, int c) {   // 128-col u16 tile
  int slot = ((c >> 3) ^ (r & 7) ^ ((r >> 3) & 15)) & 15;
  return r * 128 + slot * 8 + (c & 7);
}
static __device__ __forceinline__ int widx(int r, int c) {   // halved W table
  return (r & 64) * 128 + swzc(r & 63, c);
}
// C repack tile [o][s] u16 (qkv): b64 epilogue writes + 256B readback rows.
static __device__ __forceinline__ int cbix(int o, int s) {
  int slot = ((s >> 3) ^ (o & 15)) & 15;
  return o * 128 + slot * 8 + (s & 7);
}
static __device__ __forceinline__ int swat(int w, int x) {   // 64-col attn tile
  int slot = ((x >> 3) ^ (w & 7) ^ ((w >> 3) & 7)) & 7;
  return w * 64 + slot * 8 + (x & 7);
}
static __device__ __forceinline__ int pix(int i, int j) {    // attn P tile
  int slot = ((j >> 3) ^ (((i >> 2) & 3) << 1)) & 7;
  return i * 64 + slot * 8 + (j & 7);
}
// tail f32 chunk [64 o][128 s]: 16B-slot XOR swizzle (2-way max write,
// conflict-free b128 read). dword index.
static __device__ __forceinline__ int fdx(int o, int slot) { // slot = s>>2
  return o * 128 + ((slot ^ ((o & 7) << 2)) & 31) * 4;
}

// ---------------------------------------------------------------------------
// K0: weights f32 -> bf16 into halved swizzled tables (rows 0-63 | 64-127).
// ---------------------------------------------------------------------------
__global__ __launch_bounds__(256) void prep_w_kernel(
    const float* __restrict__ Wq, const float* __restrict__ Wk,
    const float* __restrict__ Wv, const float* __restrict__ W1,
    const float* __restrict__ W2, const float* __restrict__ W3,
    unsigned short* __restrict__ out)
{
  const float* Ws[6] = {Wq, Wk, Wv, W1, W2, W3};
  const float* W = Ws[blockIdx.x];
  unsigned short* o = out + (size_t)blockIdx.x * WTAB;
  const int tid = threadIdx.x;
#pragma unroll
  for (int p = 0; p < 16; ++p) {
    const int base = p * 1024 + tid * 4;
    const int m = base >> 7;
    const int c0 = base & 127;
    f32x4 v = *(const f32x4*)&W[base];
    u16x4 u;
#pragma unroll
    for (int e = 0; e < 4; ++e) u[e] = f2b(v[e]);
    *(u16x4*)&o[widx(m, c0)] = u;
  }
}

// ---------------------------------------------------------------------------
// K1: fused QKV. 512 WGs x 512 thr, 512-s strip/WG. W resident (96KB).
// Dual C-buffers: R1 q->cb | R2 k->xb + readback q | R3 v->cb + readback k |
// R4 readback v + stage next X. 5 barriers/sub-tile, all stores 256B bursts.
// ---------------------------------------------------------------------------
__global__ __launch_bounds__(512, 2) void qkv_kernel(
    const float* __restrict__ X, const unsigned short* __restrict__ Wbf,
    const float* __restrict__ Bq, const float* __restrict__ Bk,
    const float* __restrict__ Bv,
    unsigned short* __restrict__ Yq, unsigned short* __restrict__ Yk,
    unsigned short* __restrict__ Yv)
{
  __shared__ unsigned short wt[3 * WTAB];  // 96KB: Wq,Wk,Wv swizzled images
  __shared__ unsigned short xb[WTAB];      // 32KB: X^T stage / k repack
  __shared__ unsigned short cb[WTAB];      // 32KB: q / v repack

  const int tid  = threadIdx.x;
  const int wv   = tid >> 6;
  const int lane = tid & 63;
  const int lr   = lane & 15;
  const int lg   = lane >> 4;
  // XCD-chunked swizzle: 512 blocks -> each XCD gets 64 contiguous strips
  const int lin  = blockIdx.x;
  const int swz  = ((lin & 7) << 6) | (lin >> 3);
  const int sbase = (swz & 127) * 512;
  const size_t xoff = (size_t)(swz >> 7) * CCH * SPB;
  const int go = tid * 8;

  // ---- issue all W glds up front (12 x 16B/thread; drained at S0) ----
#pragma unroll
  for (int t = 0; t < 3; ++t)
#pragma unroll
    for (int p = 0; p < 4; ++p)
      glds16(&Wbf[t * WTAB + p * 4096 + go], &wt[t * WTAB + p * 4096 + go]);

  // ---- bias -> regs (o = of*16+lr per lane) ----
  float bq_v[8], bk_v[8], bv_v[8];
#pragma unroll
  for (int of = 0; of < 8; ++of) {
    bq_v[of] = Bq[of * 16 + lr];
    bk_v[of] = Bk[of * 16 + lr];
    bv_v[of] = Bv[of * 16 + lr];
  }

  // staging geometry: thread owns c-pair (c0,c0+1), 4x4 s-chunks
  const int c0  = (tid >> 3) * 2;
  const int sb8 = (tid & 7) * 4;
  const float* xrow = X + xoff + (size_t)c0 * SPB + sbase;
  unsigned int* xb32 = (unsigned int*)xb;

  f32x4 xr[8];
#pragma unroll
  for (int i = 0; i < 4; ++i) {
    xr[i]     = *(const f32x4*)&xrow[sb8 + 32 * i];
    xr[4 + i] = *(const f32x4*)&xrow[SPB + sb8 + 32 * i];
  }
#pragma unroll
  for (int i = 0; i < 4; ++i)
#pragma unroll
    for (int e = 0; e < 4; ++e)
      xb32[swzc(sb8 + 32 * i + e, c0) >> 1] = pk2(xr[i][e], xr[4 + i][e]);
  __syncthreads();   // S0: X0 staged, all W resident (full vm drain)

#pragma unroll
  for (int si = 0; si < 4; ++si) {
    const int sg = sbase + si * 128;

    // ---- R0: prefetch next X (T14) + A-frag reads ----
    if (si < 3) {
      const float* xn = xrow + (si + 1) * 128;
#pragma unroll
      for (int i = 0; i < 4; ++i) {
        xr[i]     = *(const f32x4*)&xn[sb8 + 32 * i];
        xr[4 + i] = *(const f32x4*)&xn[SPB + sb8 + 32 * i];
      }
    }
    u16x8 afr[4];
#pragma unroll
    for (int ks = 0; ks < 4; ++ks)
      afr[ks] = *(const u16x8*)&xb[swzc(wv * 16 + lr, ks * 32 + lg * 8)];
    bar_lgkm();   // afr reads done by all waves; xb free

    // ---- R1: GEMM_q ; repack_q -> cb ----
    {
      f32x4 acc[8];
#pragma unroll
      for (int of = 0; of < 8; ++of) { f32x4 z = {0.f,0.f,0.f,0.f}; acc[of] = z; }
#pragma unroll
      for (int ks = 0; ks < 4; ++ks) {
        const int k0 = ks * 32 + lg * 8;
#pragma unroll
        for (int of = 0; of < 8; ++of)
          acc[of] = MFMA16(afr[ks], *(const u16x8*)&wt[widx(of*16+lr, k0)], acc[of]);
      }
#pragma unroll
      for (int of = 0; of < 8; ++of) {
        const float b = bq_v[of];
        u32x2 pk;
        pk.x = pk2(acc[of][0] + b, acc[of][1] + b);
        pk.y = pk2(acc[of][2] + b, acc[of][3] + b);
        *(u32x2*)&cb[cbix(of * 16 + lr, wv * 16 + lg * 4)] = pk;
      }
    }
    bar_lgkm();   // repack_q visible

    // ---- R2: GEMM_k ; repack_k -> xb ; readback_q(cb) + store_q ----
    {
      f32x4 acc[8];
#pragma unroll
      for (int of = 0; of < 8; ++of) { f32x4 z = {0.f,0.f,0.f,0.f}; acc[of] = z; }
#pragma unroll
      for (int ks = 0; ks < 4; ++ks) {
        const int k0 = ks * 32 + lg * 8;
#pragma unroll
        for (int of = 0; of < 8; ++of)
          acc[of] = MFMA16(afr[ks], *(const u16x8*)&wt[WTAB + widx(of*16+lr, k0)], acc[of]);
      }
#pragma unroll
      for (int p = 0; p < 4; ++p) {
        const int row = p * 32 + (tid >> 4);
        const int sc  = (tid & 15) * 8;
        u16x8 v = *(const u16x8*)&cb[cbix(row, sc)];
        *(u16x8*)&Yq[xoff + (size_t)row * SPB + sg + sc] = v;
      }
#pragma unroll
      for (int of = 0; of < 8; ++of) {
        const float b = bk_v[of];
        u32x2 pk;
        pk.x = pk2(acc[of][0] + b, acc[of][1] + b);
        pk.y = pk2(acc[of][2] + b, acc[of][3] + b);
        *(u32x2*)&xb[cbix(of * 16 + lr, wv * 16 + lg * 4)] = pk;
      }
    }
    bar_lgkm();   // repack_k visible; readback_q done -> cb free

    // ---- R3: GEMM_v ; repack_v -> cb ; readback_k(xb) + store_k ----
    {
      f32x4 acc[8];
#pragma unroll
      for (int of = 0; of < 8; ++of) { f32x4 z = {0.f,0.f,0.f,0.f}; acc[of] = z; }
#pragma unroll
      for (int ks = 0; ks < 4; ++ks) {
        const int k0 = ks * 32 + lg * 8;
#pragma unroll
        for (int of = 0; of < 8; ++of)
          acc[of] = MFMA16(afr[ks], *(const u16x8*)&wt[2*WTAB + widx(of*16+lr, k0)], acc[of]);
      }
#pragma unroll
      for (int p = 0; p < 4; ++p) {
        const int row = p * 32 + (tid >> 4);
        const int sc  = (tid & 15) * 8;
        u16x8 v = *(const u16x8*)&xb[cbix(row, sc)];
        *(u16x8*)&Yk[xoff + (size_t)row * SPB + sg + sc] = v;
      }
#pragma unroll
      for (int of = 0; of < 8; ++of) {
        const float b = bv_v[of];
        u32x2 pk;
        pk.x = pk2(acc[of][0] + b, acc[of][1] + b);
        pk.y = pk2(acc[of][2] + b, acc[of][3] + b);
        *(u32x2*)&cb[cbix(of * 16 + lr, wv * 16 + lg * 4)] = pk;
      }
    }
    bar_lgkm();   // repack_v visible; readback_k done -> xb free

    // ---- R4: readback_v(cb) + store_v ; stage next X -> xb ----
#pragma unroll
    for (int p = 0; p < 4; ++p) {
      const int row = p * 32 + (tid >> 4);
      const int sc  = (tid & 15) * 8;
      u16x8 v = *(const u16x8*)&cb[cbix(row, sc)];
      *(u16x8*)&Yv[xoff + (size_t)row * SPB + sg + sc] = v;
    }
    if (si < 3) {
#pragma unroll
      for (int i = 0; i < 4; ++i)
#pragma unroll
        for (int e = 0; e < 4; ++e)
          xb32[swzc(sb8 + 32 * i + e, c0) >> 1] = pk2(xr[i][e], xr[4 + i][e]);
      bar_lgkm();   // stage visible; readback_v done -> cb free for next R1
    }
  }
}

// ---------------------------------------------------------------------------
// K2: attention per (b,c,d) 64x64 slice (unchanged).
// ---------------------------------------------------------------------------
__global__ __launch_bounds__(256, 4) void attn64_kernel(
    const unsigned short* __restrict__ Q,
    const unsigned short* __restrict__ K,
    const unsigned short* __restrict__ V,
    unsigned short* __restrict__ O)
{
  __shared__ unsigned short qt[4096];   // Q^T[w][x]
  __shared__ unsigned short kt[4096];   // K^T[w][x]
  __shared__ unsigned short vt[4096];   // V^T[w][x]
  __shared__ unsigned short pbuf[4096]; // P rows (wave-private)

  const int tid  = threadIdx.x;
  const int wv   = tid >> 6;
  const int lane = tid & 63;
  const int lr   = lane & 15;
  const int lg   = lane >> 4;
  const int bid  = blockIdx.x;                       // 8192 = 8 * 1024
  const int bs   = ((bid & 7) << 10) | (bid >> 3);   // XCD-chunked
  const size_t base = (size_t)bs * 4096;

  {
    const int x0 = (tid >> 3) * 2;
    const int w0 = (tid & 7) * 8;
    const size_t ga = base + (size_t)x0 * 64 + w0;
    u16x8 qa = *(const u16x8*)&Q[ga], qb = *(const u16x8*)&Q[ga + 64];
    u16x8 ka = *(const u16x8*)&K[ga], kb = *(const u16x8*)&K[ga + 64];
    u16x8 va = *(const u16x8*)&V[ga], vb = *(const u16x8*)&V[ga + 64];
    unsigned int* qt32 = (unsigned int*)qt;
    unsigned int* kt32 = (unsigned int*)kt;
    unsigned int* vt32 = (unsigned int*)vt;
#pragma unroll
    for (int e = 0; e < 8; ++e) {
      const int idx = swat(w0 + e, x0) >> 1;
      qt32[idx] = (unsigned int)qa[e] | ((unsigned int)qb[e] << 16);
      kt32[idx] = (unsigned int)ka[e] | ((unsigned int)kb[e] << 16);
      vt32[idx] = (unsigned int)va[e] | ((unsigned int)vb[e] << 16);
    }
  }
  __syncthreads();

  f32x4 sacc[4];
#pragma unroll
  for (int nf = 0; nf < 4; ++nf) { f32x4 z = {0.f, 0.f, 0.f, 0.f}; sacc[nf] = z; }
#pragma unroll
  for (int ks = 0; ks < 2; ++ks) {
    const int k0 = ks * 32 + lg * 8;
    u16x8 a = *(const u16x8*)&qt[swat(wv * 16 + lr, k0)];
#pragma unroll
    for (int nf = 0; nf < 4; ++nf) {
      u16x8 bb = *(const u16x8*)&kt[swat(nf * 16 + lr, k0)];
      sacc[nf] = MFMA16(a, bb, sacc[nf]);
    }
  }

#pragma unroll
  for (int r = 0; r < 4; ++r) {
    float m = fmaxf(fmaxf(sacc[0][r], sacc[1][r]), fmaxf(sacc[2][r], sacc[3][r]));
    m = fmaxf(m, __shfl_xor(m, 1));
    m = fmaxf(m, __shfl_xor(m, 2));
    m = fmaxf(m, __shfl_xor(m, 4));
    m = fmaxf(m, __shfl_xor(m, 8));
    float sum = 0.f;
#pragma unroll
    for (int nf = 0; nf < 4; ++nf) {
      float p = __expf(sacc[nf][r] - m);
      sacc[nf][r] = p;
      sum += p;
    }
    sum += __shfl_xor(sum, 1);
    sum += __shfl_xor(sum, 2);
    sum += __shfl_xor(sum, 4);
    sum += __shfl_xor(sum, 8);
    const float inv = 1.f / sum;
    const int i = wv * 16 + lg * 4 + r;
#pragma unroll
    for (int nf = 0; nf < 4; ++nf)
      pbuf[pix(i, nf * 16 + lr)] = f2b(sacc[nf][r] * inv);
  }

  f32x4 oacc[4];
#pragma unroll
  for (int nf = 0; nf < 4; ++nf) { f32x4 z = {0.f, 0.f, 0.f, 0.f}; oacc[nf] = z; }
#pragma unroll
  for (int ks = 0; ks < 2; ++ks) {
    const int k0 = ks * 32 + lg * 8;
    u16x8 a = *(const u16x8*)&pbuf[pix(wv * 16 + lr, k0)];
#pragma unroll
    for (int nf = 0; nf < 4; ++nf) {
      u16x8 bb = *(const u16x8*)&vt[swat(nf * 16 + lr, k0)];
      oacc[nf] = MFMA16(bb, a, oacc[nf]);   // swapped args
    }
  }

  {
    const size_t ib = base + (size_t)(16 * wv + lr) * 64 + lg * 4;
#pragma unroll
    for (int nf = 0; nf < 4; ++nf) {
      u32x2 pk;
      pk.x = pk2(oacc[nf][0], oacc[nf][1]);
      pk.y = pk2(oacc[nf][2], oacc[nf][3]);
      *(u32x2*)&O[ib + nf * 16] = pk;
    }
  }
}

// ---------------------------------------------------------------------------
// K3: tail a1+relu -> a2 -> f. Final f32 out via two swizzled 32KB LDS
// chunks -> 512B contiguous f32x4 bursts (was 64B direct).
// ---------------------------------------------------------------------------
__global__ __launch_bounds__(256, 2) void tail_kernel(
    const unsigned short* __restrict__ Xb, const unsigned short* __restrict__ Wbf,
    const float* __restrict__ B1, const float* __restrict__ B2,
    const float* __restrict__ B3, float* __restrict__ OUT)
{
  __shared__ unsigned short wl[16384];   // W full (halved-table image)
  __shared__ unsigned short xc[16384];   // chain tile [s][c] / f32 chunk
  __shared__ float bias_lds[3][128];
  float* fA = (float*)xc;                // [64][128] f32 chunk view

  const int tid  = threadIdx.x;
  const int wv   = tid >> 6;
  const int lane = tid & 63;
  const int lr   = lane & 15;
  const int lg   = lane >> 4;
  const int bx   = blockIdx.x;                      // 512 = 8 * 64
  const int bxs  = ((bx & 7) << 6) | (bx >> 3);     // XCD-chunked
  const int s0   = bxs * 128;
  const size_t xbase = (size_t)blockIdx.y * CCH * SPB;
  const int go = tid * 8;

#pragma unroll
  for (int p = 0; p < 8; ++p) glds16(&Wbf[p * 2048 + go], &wl[p * 2048 + go]);

  if (tid < 128) {
    bias_lds[0][tid] = B1[tid];
    bias_lds[1][tid] = B2[tid];
    bias_lds[2][tid] = B3[tid];
  }

  {
    const int cp = tid >> 2;
    const int sq = tid & 3;
    const unsigned short* xa = Xb + xbase + (size_t)(2 * cp) * SPB + s0 + sq * 32;
    const unsigned short* xb = xa + SPB;
    unsigned int* xc32 = (unsigned int*)xc;
#pragma unroll
    for (int i = 0; i < 4; ++i) {
      u16x8 a = *(const u16x8*)&xa[8 * i];
      u16x8 b = *(const u16x8*)&xb[8 * i];
#pragma unroll
      for (int e = 0; e < 8; ++e)
        xc32[swzc(sq * 32 + 8 * i + e, 2 * cp) >> 1] =
            (unsigned int)a[e] | ((unsigned int)b[e] << 16);
    }
  }
  __syncthreads();   // S1: stage + W1 resident

  u16x8 bfr[2][4];
#pragma unroll
  for (int nf = 0; nf < 2; ++nf)
#pragma unroll
    for (int ks = 0; ks < 4; ++ks)
      bfr[nf][ks] = *(const u16x8*)&xc[swzc(wv * 32 + nf * 16 + lr, ks * 32 + lg * 8)];

  f32x4 acc[8][2];
  auto gemm_std = [&]() {
#pragma unroll
    for (int mf = 0; mf < 8; ++mf)
#pragma unroll
      for (int nf = 0; nf < 2; ++nf) {
        f32x4 z = {0.f, 0.f, 0.f, 0.f};
        acc[mf][nf] = z;
      }
#pragma unroll
    for (int ks = 0; ks < 4; ++ks) {
      const int k0 = ks * 32 + lg * 8;
#pragma unroll
      for (int mf = 0; mf < 8; ++mf) {
        u16x8 afr = *(const u16x8*)&wl[widx(mf * 16 + lr, k0)];
        acc[mf][0] = MFMA16(afr, bfr[0][ks], acc[mf][0]);
        acc[mf][1] = MFMA16(afr, bfr[1][ks], acc[mf][1]);
      }
    }
  };

  auto epi_chain = [&](int ci, bool relu) {
#pragma unroll
    for (int mf = 0; mf < 8; ++mf)
#pragma unroll
      for (int nf = 0; nf < 2; ++nf) {
        const int s = wv * 32 + nf * 16 + lr;
        const int cc = mf * 16 + lg * 4;
        f32x4 bb = *(const f32x4*)&bias_lds[ci][cc];
        float v0 = acc[mf][nf][0] + bb[0];
        float v1 = acc[mf][nf][1] + bb[1];
        float v2 = acc[mf][nf][2] + bb[2];
        float v3 = acc[mf][nf][3] + bb[3];
        if (relu) {
          v0 = fmaxf(v0, 0.f); v1 = fmaxf(v1, 0.f);
          v2 = fmaxf(v2, 0.f); v3 = fmaxf(v3, 0.f);
        }
        u32x2 pk;
        pk.x = pk2(v0, v1);
        pk.y = pk2(v2, v3);
        *(u32x2*)&xc[swzc(s, cc)] = pk;
      }
#pragma unroll
    for (int nf = 0; nf < 2; ++nf)
#pragma unroll
      for (int ks = 0; ks < 4; ++ks)
        bfr[nf][ks] = *(const u16x8*)&xc[swzc(wv * 32 + nf * 16 + lr, ks * 32 + lg * 8)];
  };

#pragma unroll
  for (int j = 0; j < 2; ++j) {
    gemm_std();
    bar_lgkm();
    const unsigned short* Wn = Wbf + (size_t)(j + 1) * WTAB;
#pragma unroll
    for (int p = 0; p < 8; ++p) glds16(&Wn[p * 2048 + go], &wl[p * 2048 + go]);
    epi_chain(j, j == 0);
    bar_vm0();
  }

  // ---- final GEMM swapped: D[s][o] per lane ----
  {
    f32x4 acc3[2][8];
#pragma unroll
    for (int sf = 0; sf < 2; ++sf)
#pragma unroll
      for (int of = 0; of < 8; ++of) {
        f32x4 z = {0.f, 0.f, 0.f, 0.f};
        acc3[sf][of] = z;
      }
#pragma unroll
    for (int ks = 0; ks < 4; ++ks) {
      const int k0 = ks * 32 + lg * 8;
#pragma unroll
      for (int of = 0; of < 8; ++of) {
        u16x8 wfr = *(const u16x8*)&wl[widx(of * 16 + lr, k0)];
        acc3[0][of] = MFMA16(bfr[0][ks], wfr, acc3[0][of]);
        acc3[1][of] = MFMA16(bfr[1][ks], wfr, acc3[1][of]);
      }
    }

    // ---- two swizzled 32KB f32 chunks -> 512B contiguous bursts ----
#pragma unroll
    for (int half = 0; half < 2; ++half) {
      // write: b128 per (sf, of4); o_local = of4*16+lr, s = wv*32+sf*16+lg*4
#pragma unroll
      for (int sf = 0; sf < 2; ++sf)
#pragma unroll
        for (int of4 = 0; of4 < 4; ++of4) {
          const int of = half * 4 + of4;
          const int ol = of4 * 16 + lr;
          const int slot = wv * 8 + sf * 4 + lg;
          const float b = bias_lds[2][of * 16 + lr];
          f32x4 v = acc3[sf][of];
          v[0] += b; v[1] += b; v[2] += b; v[3] += b;
          *(f32x4*)&fA[fdx(ol, slot)] = v;
        }
      bar_lgkm();   // chunk visible
      // readback: 8 passes, 2 rows x 512B contiguous per wave-instr
#pragma unroll
      for (int p = 0; p < 8; ++p) {
        const int r  = p * 8 + (tid >> 5);
        const int cg = tid & 31;
        f32x4 v = *(const f32x4*)&fA[fdx(r, cg)];
        *(f32x4*)&OUT[xbase + (size_t)(r + half * 64) * SPB + s0 + cg * 4] = v;
      }
      if (half == 0) bar_lgkm();   // readback done before overwrite
    }
  }
}

extern "C" void kernel_launch(void* const* d_in, const int* in_sizes, int n_in,
                              void* d_out, int out_size, void* d_ws, size_t ws_size,
                              hipStream_t stream) {
  const float* x   = (const float*)d_in[0];
  const float* Wq  = (const float*)d_in[1];  const float* bq  = (const float*)d_in[2];
  const float* Wk  = (const float*)d_in[3];  const float* bk  = (const float*)d_in[4];
  const float* Wv  = (const float*)d_in[5];  const float* bv  = (const float*)d_in[6];
  const float* Wa1 = (const float*)d_in[7];  const float* ba1 = (const float*)d_in[8];
  const float* Wa2 = (const float*)d_in[9];  const float* ba2 = (const float*)d_in[10];
  const float* Wf  = (const float*)d_in[11]; const float* bf_ = (const float*)d_in[12];

  // ws layout: q (67.1MB) then 6 bf16 weight tables (192KB).
  unsigned short* qb  = (unsigned short*)d_ws;
  unsigned short* wbf = qb + (size_t)NBATCH * CCH * SPB;
  // k,v packed into d_out (dead before final f32 write).
  unsigned short* kb = (unsigned short*)d_out;
  unsigned short* vb = kb + (size_t)NBATCH * CCH * SPB;

  prep_w_kernel<<<6, 256, 0, stream>>>(Wq, Wk, Wv, Wa1, Wa2, Wf, wbf);

  qkv_kernel<<<512, 512, 0, stream>>>(x, wbf, bq, bk, bv, qb, kb, vb);

  attn64_kernel<<<NBATCH * CCH * 16, 256, 0, stream>>>(qb, kb, vb, qb);

  tail_kernel<<<dim3(SPB / 128, NBATCH), 256, 0, stream>>>(
      qb, wbf + (size_t)3 * WTAB, ba1, ba2, bf_, (float*)d_out);
}

// Round 12
// 176.945 us; speedup vs baseline: 1.6675x; 1.0419x over previous
//
#include <hip/hip_runtime.h>

// SelfAttention3d: B=4, C=128, D=16, H=W=64.
//   q/k/v scratch uses TILED layout [b][s/128][c][s%128]: each 128-s
//   sub-tile is a contiguous 32KB block -> qkv stores are sequential DRAM
//   bursts (the write-side analog of R7's read-locality fix).
//   K0 prep  : 6 weight mats f32 -> bf16, pre-swizzled halved tables in ws
//   K1 qkv   : 512-s strip/WG, W resident (96KB) + dual C-buffers
//   K2 attn  : per (b,c,d) 64x64; tiled-layout addressing; O tiled in-place
//   K3 tail  : reads one 32KB tile contiguously; f32 out via swizzled LDS

#define CCH 128
#define SPB 65536      // per-batch spatial = D*H*W
#define NBATCH 4
#define WTAB 16384     // elements per 128x128 weight table
#define TSZ  16384     // elements per [c][128] tile (CCH*128)

typedef float f32x4 __attribute__((ext_vector_type(4)));
typedef __bf16 bf16x8 __attribute__((ext_vector_type(8)));
typedef short s16x8 __attribute__((ext_vector_type(8)));
typedef unsigned short u16x8 __attribute__((ext_vector_type(8)));
typedef unsigned short u16x4 __attribute__((ext_vector_type(4)));
typedef unsigned int u32x2 __attribute__((ext_vector_type(2)));

// ---- MFMA wrapper: robust to builtin signature (v8i16 vs v8bf16) ----
template <typename T>
static __device__ __forceinline__ auto mfma_try(T a, T b, f32x4 c, int)
    -> decltype(__builtin_amdgcn_mfma_f32_16x16x32_bf16(a, b, c, 0, 0, 0)) {
  return __builtin_amdgcn_mfma_f32_16x16x32_bf16(a, b, c, 0, 0, 0);
}
template <typename T>
static __device__ __forceinline__ f32x4 mfma_try(T a, T b, f32x4 c, long) {
  return __builtin_amdgcn_mfma_f32_16x16x32_bf16(
      __builtin_bit_cast(bf16x8, a), __builtin_bit_cast(bf16x8, b), c, 0, 0, 0);
}
static __device__ __forceinline__ f32x4 MFMA16(u16x8 a, u16x8 b, f32x4 c) {
  return mfma_try(__builtin_bit_cast(s16x8, a), __builtin_bit_cast(s16x8, b), c, 0);
}

static __device__ __forceinline__ unsigned short f2b(float f) {
  return __builtin_bit_cast(unsigned short, (__bf16)f);
}
static __device__ __forceinline__ unsigned int pk2(float a, float b) {
  return (unsigned int)f2b(a) | ((unsigned int)f2b(b) << 16);
}

// async global->LDS, 16B per lane (linear dest, pre-swizzled source tables)
static __device__ __forceinline__ void glds16(const unsigned short* g,
                                              unsigned short* l) {
  __builtin_amdgcn_global_load_lds(
      (const __attribute__((address_space(1))) unsigned int*)g,
      (__attribute__((address_space(3))) unsigned int*)l, 16, 0, 0);
}

// lgkm-only barrier: LDS ordering without draining stores (T4 pattern)
static __device__ __forceinline__ void bar_lgkm() {
  asm volatile("s_waitcnt lgkmcnt(0)" ::: "memory");
  __builtin_amdgcn_sched_barrier(0);
  __builtin_amdgcn_s_barrier();
  __builtin_amdgcn_sched_barrier(0);
}
static __device__ __forceinline__ void bar_vm0() {
  asm volatile("s_waitcnt vmcnt(0)" ::: "memory");
  __builtin_amdgcn_sched_barrier(0);
  __builtin_amdgcn_s_barrier();
  __builtin_amdgcn_sched_barrier(0);
}

// --- swizzles (element index), bijective per row ---
static __device__ __forceinline__ int swzc(int r, int c) {   // 128-col u16 tile
  int slot = ((c >> 3) ^ (r & 7) ^ ((r >> 3) & 15)) & 15;
  return r * 128 + slot * 8 + (c & 7);
}
static __device__ __forceinline__ int widx(int r, int c) {   // halved W table
  return (r & 64) * 128 + swzc(r & 63, c);
}
// C repack tile [o][s] u16 (qkv): b64 epilogue writes + 256B readback rows.
static __device__ __forceinline__ int cbix(int o, int s) {
  int slot = ((s >> 3) ^ (o & 15)) & 15;
  return o * 128 + slot * 8 + (s & 7);
}
static __device__ __forceinline__ int swat(int w, int x) {   // 64-col attn tile
  int slot = ((x >> 3) ^ (w & 7) ^ ((w >> 3) & 7)) & 7;
  return w * 64 + slot * 8 + (x & 7);
}
static __device__ __forceinline__ int pix(int i, int j) {    // attn P tile
  int slot = ((j >> 3) ^ (((i >> 2) & 3) << 1)) & 7;
  return i * 64 + slot * 8 + (j & 7);
}
// tail f32 chunk [64 o][128 s]: 16B-slot XOR swizzle. dword index.
static __device__ __forceinline__ int fdx(int o, int slot) { // slot = s>>2
  return o * 128 + ((slot ^ ((o & 7) << 2)) & 31) * 4;
}

// ---------------------------------------------------------------------------
// K0: weights f32 -> bf16 into halved swizzled tables (rows 0-63 | 64-127).
// ---------------------------------------------------------------------------
__global__ __launch_bounds__(256) void prep_w_kernel(
    const float* __restrict__ Wq, const float* __restrict__ Wk,
    const float* __restrict__ Wv, const float* __restrict__ W1,
    const float* __restrict__ W2, const float* __restrict__ W3,
    unsigned short* __restrict__ out)
{
  const float* Ws[6] = {Wq, Wk, Wv, W1, W2, W3};
  const float* W = Ws[blockIdx.x];
  unsigned short* o = out + (size_t)blockIdx.x * WTAB;
  const int tid = threadIdx.x;
#pragma unroll
  for (int p = 0; p < 16; ++p) {
    const int base = p * 1024 + tid * 4;
    const int m = base >> 7;
    const int c0 = base & 127;
    f32x4 v = *(const f32x4*)&W[base];
    u16x4 u;
#pragma unroll
    for (int e = 0; e < 4; ++e) u[e] = f2b(v[e]);
    *(u16x4*)&o[widx(m, c0)] = u;
  }
}

// ---------------------------------------------------------------------------
// K1: fused QKV. 512 WGs x 512 thr, 512-s strip/WG. W resident (96KB).
// Dual C-buffers; outputs stored TILED: one contiguous 32KB block per
// conv-subtile (sequential DRAM bursts).
// ---------------------------------------------------------------------------
__global__ __launch_bounds__(512, 2) void qkv_kernel(
    const float* __restrict__ X, const unsigned short* __restrict__ Wbf,
    const float* __restrict__ Bq, const float* __restrict__ Bk,
    const float* __restrict__ Bv,
    unsigned short* __restrict__ Yq, unsigned short* __restrict__ Yk,
    unsigned short* __restrict__ Yv)
{
  __shared__ unsigned short wt[3 * WTAB];  // 96KB: Wq,Wk,Wv swizzled images
  __shared__ unsigned short xb[WTAB];      // 32KB: X^T stage / k repack
  __shared__ unsigned short cb[WTAB];      // 32KB: q / v repack

  const int tid  = threadIdx.x;
  const int wv   = tid >> 6;
  const int lane = tid & 63;
  const int lr   = lane & 15;
  const int lg   = lane >> 4;
  // XCD-chunked swizzle: 512 blocks -> each XCD gets 64 contiguous strips
  const int lin  = blockIdx.x;
  const int swz  = ((lin & 7) << 6) | (lin >> 3);
  const int sbase = (swz & 127) * 512;
  const size_t xoff = (size_t)(swz >> 7) * CCH * SPB;
  const int go = tid * 8;

  // ---- issue all W glds up front (12 x 16B/thread; drained at S0) ----
#pragma unroll
  for (int t = 0; t < 3; ++t)
#pragma unroll
    for (int p = 0; p < 4; ++p)
      glds16(&Wbf[t * WTAB + p * 4096 + go], &wt[t * WTAB + p * 4096 + go]);

  // ---- bias -> regs (o = of*16+lr per lane) ----
  float bq_v[8], bk_v[8], bv_v[8];
#pragma unroll
  for (int of = 0; of < 8; ++of) {
    bq_v[of] = Bq[of * 16 + lr];
    bk_v[of] = Bk[of * 16 + lr];
    bv_v[of] = Bv[of * 16 + lr];
  }

  // staging geometry: thread owns c-pair (c0,c0+1), 4x4 s-chunks
  const int c0  = (tid >> 3) * 2;
  const int sb8 = (tid & 7) * 4;
  const float* xrow = X + xoff + (size_t)c0 * SPB + sbase;
  unsigned int* xb32 = (unsigned int*)xb;

  f32x4 xr[8];
#pragma unroll
  for (int i = 0; i < 4; ++i) {
    xr[i]     = *(const f32x4*)&xrow[sb8 + 32 * i];
    xr[4 + i] = *(const f32x4*)&xrow[SPB + sb8 + 32 * i];
  }
#pragma unroll
  for (int i = 0; i < 4; ++i)
#pragma unroll
    for (int e = 0; e < 4; ++e)
      xb32[swzc(sb8 + 32 * i + e, c0) >> 1] = pk2(xr[i][e], xr[4 + i][e]);
  __syncthreads();   // S0: X0 staged, all W resident (full vm drain)

#pragma unroll
  for (int si = 0; si < 4; ++si) {
    // tiled output base: tile index = (batch*512) + strip*4 + si
    const size_t yb =
        ((size_t)(swz >> 7) * 512 + (size_t)(swz & 127) * 4 + si) * TSZ;

    // ---- R0: prefetch next X (T14) + A-frag reads ----
    if (si < 3) {
      const float* xn = xrow + (si + 1) * 128;
#pragma unroll
      for (int i = 0; i < 4; ++i) {
        xr[i]     = *(const f32x4*)&xn[sb8 + 32 * i];
        xr[4 + i] = *(const f32x4*)&xn[SPB + sb8 + 32 * i];
      }
    }
    u16x8 afr[4];
#pragma unroll
    for (int ks = 0; ks < 4; ++ks)
      afr[ks] = *(const u16x8*)&xb[swzc(wv * 16 + lr, ks * 32 + lg * 8)];
    bar_lgkm();   // afr reads done by all waves; xb free

    // ---- R1: GEMM_q ; repack_q -> cb ----
    {
      f32x4 acc[8];
#pragma unroll
      for (int of = 0; of < 8; ++of) { f32x4 z = {0.f,0.f,0.f,0.f}; acc[of] = z; }
#pragma unroll
      for (int ks = 0; ks < 4; ++ks) {
        const int k0 = ks * 32 + lg * 8;
#pragma unroll
        for (int of = 0; of < 8; ++of)
          acc[of] = MFMA16(afr[ks], *(const u16x8*)&wt[widx(of*16+lr, k0)], acc[of]);
      }
#pragma unroll
      for (int of = 0; of < 8; ++of) {
        const float b = bq_v[of];
        u32x2 pk;
        pk.x = pk2(acc[of][0] + b, acc[of][1] + b);
        pk.y = pk2(acc[of][2] + b, acc[of][3] + b);
        *(u32x2*)&cb[cbix(of * 16 + lr, wv * 16 + lg * 4)] = pk;
      }
    }
    bar_lgkm();   // repack_q visible

    // ---- R2: GEMM_k ; repack_k -> xb ; readback_q(cb) + store_q ----
    {
      f32x4 acc[8];
#pragma unroll
      for (int of = 0; of < 8; ++of) { f32x4 z = {0.f,0.f,0.f,0.f}; acc[of] = z; }
#pragma unroll
      for (int ks = 0; ks < 4; ++ks) {
        const int k0 = ks * 32 + lg * 8;
#pragma unroll
        for (int of = 0; of < 8; ++of)
          acc[of] = MFMA16(afr[ks], *(const u16x8*)&wt[WTAB + widx(of*16+lr, k0)], acc[of]);
      }
#pragma unroll
      for (int p = 0; p < 4; ++p) {
        const int row = p * 32 + (tid >> 4);
        const int sc  = (tid & 15) * 8;
        u16x8 v = *(const u16x8*)&cb[cbix(row, sc)];
        *(u16x8*)&Yq[yb + row * 128 + sc] = v;
      }
#pragma unroll
      for (int of = 0; of < 8; ++of) {
        const float b = bk_v[of];
        u32x2 pk;
        pk.x = pk2(acc[of][0] + b, acc[of][1] + b);
        pk.y = pk2(acc[of][2] + b, acc[of][3] + b);
        *(u32x2*)&xb[cbix(of * 16 + lr, wv * 16 + lg * 4)] = pk;
      }
    }
    bar_lgkm();   // repack_k visible; readback_q done -> cb free

    // ---- R3: GEMM_v ; repack_v -> cb ; readback_k(xb) + store_k ----
    {
      f32x4 acc[8];
#pragma unroll
      for (int of = 0; of < 8; ++of) { f32x4 z = {0.f,0.f,0.f,0.f}; acc[of] = z; }
#pragma unroll
      for (int ks = 0; ks < 4; ++ks) {
        const int k0 = ks * 32 + lg * 8;
#pragma unroll
        for (int of = 0; of < 8; ++of)
          acc[of] = MFMA16(afr[ks], *(const u16x8*)&wt[2*WTAB + widx(of*16+lr, k0)], acc[of]);
      }
#pragma unroll
      for (int p = 0; p < 4; ++p) {
        const int row = p * 32 + (tid >> 4);
        const int sc  = (tid & 15) * 8;
        u16x8 v = *(const u16x8*)&xb[cbix(row, sc)];
        *(u16x8*)&Yk[yb + row * 128 + sc] = v;
      }
#pragma unroll
      for (int of = 0; of < 8; ++of) {
        const float b = bv_v[of];
        u32x2 pk;
        pk.x = pk2(acc[of][0] + b, acc[of][1] + b);
        pk.y = pk2(acc[of][2] + b, acc[of][3] + b);
        *(u32x2*)&cb[cbix(of * 16 + lr, wv * 16 + lg * 4)] = pk;
      }
    }
    bar_lgkm();   // repack_v visible; readback_k done -> xb free

    // ---- R4: readback_v(cb) + store_v ; stage next X -> xb ----
#pragma unroll
    for (int p = 0; p < 4; ++p) {
      const int row = p * 32 + (tid >> 4);
      const int sc  = (tid & 15) * 8;
      u16x8 v = *(const u16x8*)&cb[cbix(row, sc)];
      *(u16x8*)&Yv[yb + row * 128 + sc] = v;
    }
    if (si < 3) {
#pragma unroll
      for (int i = 0; i < 4; ++i)
#pragma unroll
        for (int e = 0; e < 4; ++e)
          xb32[swzc(sb8 + 32 * i + e, c0) >> 1] = pk2(xr[i][e], xr[4 + i][e]);
      bar_lgkm();   // stage visible; readback_v done -> cb free for next R1
    }
  }
}

// ---------------------------------------------------------------------------
// K2: attention per (b,c,d) 64x64 slice. Tiled q/k/v addressing; O written
// tiled in-place over q (same address map -> no cross-WG hazard).
// ---------------------------------------------------------------------------
__global__ __launch_bounds__(256, 4) void attn64_kernel(
    const unsigned short* __restrict__ Q,
    const unsigned short* __restrict__ K,
    const unsigned short* __restrict__ V,
    unsigned short* __restrict__ O)
{
  __shared__ unsigned short qt[4096];   // Q^T[w][x]
  __shared__ unsigned short kt[4096];   // K^T[w][x]
  __shared__ unsigned short vt[4096];   // V^T[w][x]
  __shared__ unsigned short pbuf[4096]; // P rows (wave-private)

  const int tid  = threadIdx.x;
  const int wv   = tid >> 6;
  const int lane = tid & 63;
  const int lr   = lane & 15;
  const int lg   = lane >> 4;
  const int bid  = blockIdx.x;                       // 8192 = 8 * 1024
  const int bs   = ((bid & 7) << 10) | (bid >> 3);   // XCD-chunked
  const int b_   = bs >> 11;
  const int c_   = (bs >> 4) & 127;
  const int d_   = bs & 15;
  // slice element hw -> Q[tb + (hw>>7)*TSZ + (hw&127)]
  const size_t tb = ((size_t)b_ * 512 + (size_t)d_ * 32) * TSZ + (size_t)c_ * 128;

  {
    const int x0 = (tid >> 3) * 2;   // even h-row
    const int w0 = (tid & 7) * 8;
    // rows x0, x0+1 live in tile x0>>1 at offsets w0 and 64+w0
    const size_t ga = tb + (size_t)(x0 >> 1) * TSZ + w0;
    u16x8 qa = *(const u16x8*)&Q[ga], qb = *(const u16x8*)&Q[ga + 64];
    u16x8 ka = *(const u16x8*)&K[ga], kb = *(const u16x8*)&K[ga + 64];
    u16x8 va = *(const u16x8*)&V[ga], vb = *(const u16x8*)&V[ga + 64];
    unsigned int* qt32 = (unsigned int*)qt;
    unsigned int* kt32 = (unsigned int*)kt;
    unsigned int* vt32 = (unsigned int*)vt;
#pragma unroll
    for (int e = 0; e < 8; ++e) {
      const int idx = swat(w0 + e, x0) >> 1;
      qt32[idx] = (unsigned int)qa[e] | ((unsigned int)qb[e] << 16);
      kt32[idx] = (unsigned int)ka[e] | ((unsigned int)kb[e] << 16);
      vt32[idx] = (unsigned int)va[e] | ((unsigned int)vb[e] << 16);
    }
  }
  __syncthreads();

  f32x4 sacc[4];
#pragma unroll
  for (int nf = 0; nf < 4; ++nf) { f32x4 z = {0.f, 0.f, 0.f, 0.f}; sacc[nf] = z; }
#pragma unroll
  for (int ks = 0; ks < 2; ++ks) {
    const int k0 = ks * 32 + lg * 8;
    u16x8 a = *(const u16x8*)&qt[swat(wv * 16 + lr, k0)];
#pragma unroll
    for (int nf = 0; nf < 4; ++nf) {
      u16x8 bb = *(const u16x8*)&kt[swat(nf * 16 + lr, k0)];
      sacc[nf] = MFMA16(a, bb, sacc[nf]);
    }
  }

#pragma unroll
  for (int r = 0; r < 4; ++r) {
    float m = fmaxf(fmaxf(sacc[0][r], sacc[1][r]), fmaxf(sacc[2][r], sacc[3][r]));
    m = fmaxf(m, __shfl_xor(m, 1));
    m = fmaxf(m, __shfl_xor(m, 2));
    m = fmaxf(m, __shfl_xor(m, 4));
    m = fmaxf(m, __shfl_xor(m, 8));
    float sum = 0.f;
#pragma unroll
    for (int nf = 0; nf < 4; ++nf) {
      float p = __expf(sacc[nf][r] - m);
      sacc[nf][r] = p;
      sum += p;
    }
    sum += __shfl_xor(sum, 1);
    sum += __shfl_xor(sum, 2);
    sum += __shfl_xor(sum, 4);
    sum += __shfl_xor(sum, 8);
    const float inv = 1.f / sum;
    const int i = wv * 16 + lg * 4 + r;
#pragma unroll
    for (int nf = 0; nf < 4; ++nf)
      pbuf[pix(i, nf * 16 + lr)] = f2b(sacc[nf][r] * inv);
  }

  f32x4 oacc[4];
#pragma unroll
  for (int nf = 0; nf < 4; ++nf) { f32x4 z = {0.f, 0.f, 0.f, 0.f}; oacc[nf] = z; }
#pragma unroll
  for (int ks = 0; ks < 2; ++ks) {
    const int k0 = ks * 32 + lg * 8;
    u16x8 a = *(const u16x8*)&pbuf[pix(wv * 16 + lr, k0)];
#pragma unroll
    for (int nf = 0; nf < 4; ++nf) {
      u16x8 bb = *(const u16x8*)&vt[swat(nf * 16 + lr, k0)];
      oacc[nf] = MFMA16(bb, a, oacc[nf]);   // swapped args
    }
  }

  {
    // O element (i, j): hw = i*64 + j -> tile i>>1, offset (i&1)*64 + j
    const int i = 16 * wv + lr;
    const size_t ib = tb + (size_t)(i >> 1) * TSZ + (size_t)(i & 1) * 64 + lg * 4;
#pragma unroll
    for (int nf = 0; nf < 4; ++nf) {
      u32x2 pk;
      pk.x = pk2(oacc[nf][0], oacc[nf][1]);
      pk.y = pk2(oacc[nf][2], oacc[nf][3]);
      *(u32x2*)&O[ib + nf * 16] = pk;
    }
  }
}

// ---------------------------------------------------------------------------
// K3: tail a1+relu -> a2 -> f. Input = one contiguous 32KB tile. Final f32
// out via two swizzled 32KB LDS chunks -> 512B contiguous bursts.
// ---------------------------------------------------------------------------
__global__ __launch_bounds__(256, 2) void tail_kernel(
    const unsigned short* __restrict__ Xb, const unsigned short* __restrict__ Wbf,
    const float* __restrict__ B1, const float* __restrict__ B2,
    const float* __restrict__ B3, float* __restrict__ OUT)
{
  __shared__ unsigned short wl[16384];   // W full (halved-table image)
  __shared__ unsigned short xc[16384];   // chain tile [s][c] / f32 chunk
  __shared__ float bias_lds[3][128];
  float* fA = (float*)xc;                // [64][128] f32 chunk view

  const int tid  = threadIdx.x;
  const int wv   = tid >> 6;
  const int lane = tid & 63;
  const int lr   = lane & 15;
  const int lg   = lane >> 4;
  const int bx   = blockIdx.x;                      // 512 = 8 * 64
  const int bxs  = ((bx & 7) << 6) | (bx >> 3);     // XCD-chunked
  const int s0   = bxs * 128;
  const size_t xbase = (size_t)blockIdx.y * CCH * SPB;     // f32 OUT (linear)
  const size_t tbin  = ((size_t)blockIdx.y * 512 + bxs) * TSZ;  // tiled input
  const int go = tid * 8;

#pragma unroll
  for (int p = 0; p < 8; ++p) glds16(&Wbf[p * 2048 + go], &wl[p * 2048 + go]);

  if (tid < 128) {
    bias_lds[0][tid] = B1[tid];
    bias_lds[1][tid] = B2[tid];
    bias_lds[2][tid] = B3[tid];
  }

  {
    const int cp = tid >> 2;
    const int sq = tid & 3;
    const unsigned short* xa = Xb + tbin + (size_t)(2 * cp) * 128 + sq * 32;
    const unsigned short* xb = xa + 128;
    unsigned int* xc32 = (unsigned int*)xc;
#pragma unroll
    for (int i = 0; i < 4; ++i) {
      u16x8 a = *(const u16x8*)&xa[8 * i];
      u16x8 b = *(const u16x8*)&xb[8 * i];
#pragma unroll
      for (int e = 0; e < 8; ++e)
        xc32[swzc(sq * 32 + 8 * i + e, 2 * cp) >> 1] =
            (unsigned int)a[e] | ((unsigned int)b[e] << 16);
    }
  }
  __syncthreads();   // S1: stage + W1 resident

  u16x8 bfr[2][4];
#pragma unroll
  for (int nf = 0; nf < 2; ++nf)
#pragma unroll
    for (int ks = 0; ks < 4; ++ks)
      bfr[nf][ks] = *(const u16x8*)&xc[swzc(wv * 32 + nf * 16 + lr, ks * 32 + lg * 8)];

  f32x4 acc[8][2];
  auto gemm_std = [&]() {
#pragma unroll
    for (int mf = 0; mf < 8; ++mf)
#pragma unroll
      for (int nf = 0; nf < 2; ++nf) {
        f32x4 z = {0.f, 0.f, 0.f, 0.f};
        acc[mf][nf] = z;
      }
#pragma unroll
    for (int ks = 0; ks < 4; ++ks) {
      const int k0 = ks * 32 + lg * 8;
#pragma unroll
      for (int mf = 0; mf < 8; ++mf) {
        u16x8 afr = *(const u16x8*)&wl[widx(mf * 16 + lr, k0)];
        acc[mf][0] = MFMA16(afr, bfr[0][ks], acc[mf][0]);
        acc[mf][1] = MFMA16(afr, bfr[1][ks], acc[mf][1]);
      }
    }
  };

  auto epi_chain = [&](int ci, bool relu) {
#pragma unroll
    for (int mf = 0; mf < 8; ++mf)
#pragma unroll
      for (int nf = 0; nf < 2; ++nf) {
        const int s = wv * 32 + nf * 16 + lr;
        const int cc = mf * 16 + lg * 4;
        f32x4 bb = *(const f32x4*)&bias_lds[ci][cc];
        float v0 = acc[mf][nf][0] + bb[0];
        float v1 = acc[mf][nf][1] + bb[1];
        float v2 = acc[mf][nf][2] + bb[2];
        float v3 = acc[mf][nf][3] + bb[3];
        if (relu) {
          v0 = fmaxf(v0, 0.f); v1 = fmaxf(v1, 0.f);
          v2 = fmaxf(v2, 0.f); v3 = fmaxf(v3, 0.f);
        }
        u32x2 pk;
        pk.x = pk2(v0, v1);
        pk.y = pk2(v2, v3);
        *(u32x2*)&xc[swzc(s, cc)] = pk;
      }
#pragma unroll
    for (int nf = 0; nf < 2; ++nf)
#pragma unroll
      for (int ks = 0; ks < 4; ++ks)
        bfr[nf][ks] = *(const u16x8*)&xc[swzc(wv * 32 + nf * 16 + lr, ks * 32 + lg * 8)];
  };

#pragma unroll
  for (int j = 0; j < 2; ++j) {
    gemm_std();
    bar_lgkm();
    const unsigned short* Wn = Wbf + (size_t)(j + 1) * WTAB;
#pragma unroll
    for (int p = 0; p < 8; ++p) glds16(&Wn[p * 2048 + go], &wl[p * 2048 + go]);
    epi_chain(j, j == 0);
    bar_vm0();
  }

  // ---- final GEMM swapped: D[s][o] per lane ----
  {
    f32x4 acc3[2][8];
#pragma unroll
    for (int sf = 0; sf < 2; ++sf)
#pragma unroll
      for (int of = 0; of < 8; ++of) {
        f32x4 z = {0.f, 0.f, 0.f, 0.f};
        acc3[sf][of] = z;
      }
#pragma unroll
    for (int ks = 0; ks < 4; ++ks) {
      const int k0 = ks * 32 + lg * 8;
#pragma unroll
      for (int of = 0; of < 8; ++of) {
        u16x8 wfr = *(const u16x8*)&wl[widx(of * 16 + lr, k0)];
        acc3[0][of] = MFMA16(bfr[0][ks], wfr, acc3[0][of]);
        acc3[1][of] = MFMA16(bfr[1][ks], wfr, acc3[1][of]);
      }
    }

    // ---- two swizzled 32KB f32 chunks -> 512B contiguous bursts ----
#pragma unroll
    for (int half = 0; half < 2; ++half) {
#pragma unroll
      for (int sf = 0; sf < 2; ++sf)
#pragma unroll
        for (int of4 = 0; of4 < 4; ++of4) {
          const int of = half * 4 + of4;
          const int ol = of4 * 16 + lr;
          const int slot = wv * 8 + sf * 4 + lg;
          const float b = bias_lds[2][of * 16 + lr];
          f32x4 v = acc3[sf][of];
          v[0] += b; v[1] += b; v[2] += b; v[3] += b;
          *(f32x4*)&fA[fdx(ol, slot)] = v;
        }
      bar_lgkm();   // chunk visible
#pragma unroll
      for (int p = 0; p < 8; ++p) {
        const int r  = p * 8 + (tid >> 5);
        const int cg = tid & 31;
        f32x4 v = *(const f32x4*)&fA[fdx(r, cg)];
        *(f32x4*)&OUT[xbase + (size_t)(r + half * 64) * SPB + s0 + cg * 4] = v;
      }
      if (half == 0) bar_lgkm();   // readback done before overwrite
    }
  }
}

extern "C" void kernel_launch(void* const* d_in, const int* in_sizes, int n_in,
                              void* d_out, int out_size, void* d_ws, size_t ws_size,
                              hipStream_t stream) {
  const float* x   = (const float*)d_in[0];
  const float* Wq  = (const float*)d_in[1];  const float* bq  = (const float*)d_in[2];
  const float* Wk  = (const float*)d_in[3];  const float* bk  = (const float*)d_in[4];
  const float* Wv  = (const float*)d_in[5];  const float* bv  = (const float*)d_in[6];
  const float* Wa1 = (const float*)d_in[7];  const float* ba1 = (const float*)d_in[8];
  const float* Wa2 = (const float*)d_in[9];  const float* ba2 = (const float*)d_in[10];
  const float* Wf  = (const float*)d_in[11]; const float* bf_ = (const float*)d_in[12];

  // ws layout: q (67.1MB, tiled) then 6 bf16 weight tables (192KB).
  unsigned short* qb  = (unsigned short*)d_ws;
  unsigned short* wbf = qb + (size_t)NBATCH * CCH * SPB;
  // k,v packed into d_out (tiled; dead before final f32 write).
  unsigned short* kb = (unsigned short*)d_out;
  unsigned short* vb = kb + (size_t)NBATCH * CCH * SPB;

  prep_w_kernel<<<6, 256, 0, stream>>>(Wq, Wk, Wv, Wa1, Wa2, Wf, wbf);

  qkv_kernel<<<512, 512, 0, stream>>>(x, wbf, bq, bk, bv, qb, kb, vb);

  attn64_kernel<<<NBATCH * CCH * 16, 256, 0, stream>>>(qb, kb, vb, qb);

  tail_kernel<<<dim3(SPB / 128, NBATCH), 256, 0, stream>>>(
      qb, wbf + (size_t)3 * WTAB, ba1, ba2, bf_, (float*)d_out);
}